// Round 5
// baseline (200.047 us; speedup 1.0000x reference)
//
#include <hip/hip_runtime.h>

// Problem constants (B=4, C=256, H=W=64 -> T=4096)
constexpr int kB  = 4;
constexpr int kC  = 256;
constexpr int kT  = 4096;
constexpr int kG  = 16;
constexpr int kCg = kC / kG;   // 16 channels per group
constexpr int kH  = 4;         // heads
constexpr int kCh = kC / kH;   // 64 channels per head
constexpr float kEps = 1e-5f;
// q scale: 1/8 (=scale^2) folded with log2(e) for exp2-domain softmax
constexpr float kQScale = 0.125f * 1.4426950408889634f;

typedef short bf16x8 __attribute__((ext_vector_type(8)));
typedef float f32x4  __attribute__((ext_vector_type(4)));
typedef float f32x16 __attribute__((ext_vector_type(16)));

__device__ inline unsigned short f2bf(float f) {
    union { float f; unsigned u; } v; v.f = f;
    unsigned r = v.u + 0x7fffu + ((v.u >> 16) & 1u);   // RNE
    return (unsigned short)(r >> 16);
}
__device__ inline unsigned pk2bf(float a, float b) {
    return (unsigned)f2bf(a) | ((unsigned)f2bf(b) << 16);
}
// truncating pack of two fp32 -> bf16x2 in ONE v_perm_b32 (high halves)
__device__ inline unsigned pk2bf_trunc(float a, float b) {
    return __builtin_amdgcn_perm(__float_as_uint(b), __float_as_uint(a), 0x07060302u);
}
// v_permlane32_swap_b32: a[32:63] <-> b[0:31].
__device__ inline void pls32(unsigned& a, unsigned& b) {
    __asm__("v_permlane32_swap_b32 %0, %1" : "+v"(a), "+v"(b));
}

// ---------------------------------------------------------------------------
// Kernel 1: GroupNorm statistics (blocks 0..63) + weight fp32->bf16 convert
// (blocks 64..191) fused into one launch.
// ---------------------------------------------------------------------------
__global__ __launch_bounds__(256) void prep_kernel(const float* __restrict__ x,
                                                   float* __restrict__ stats,
                                                   const float* __restrict__ qkv_w,
                                                   const float* __restrict__ proj_w,
                                                   unsigned short* __restrict__ wbf) {
    int tid = threadIdx.x;
    if (blockIdx.x >= 64) {
        int gid = (blockIdx.x - 64) * 256 + tid;
        for (int i = gid; i < 65536; i += 128 * 256) {
            float4 v = (i < 49152) ? ((const float4*)qkv_w)[i]
                                   : ((const float4*)proj_w)[i - 49152];
            *(uint2*)&wbf[(size_t)i * 4] = make_uint2(pk2bf(v.x, v.y), pk2bf(v.z, v.w));
        }
        return;
    }
    int bg = blockIdx.x;
    const float4* xp4 = (const float4*)(x + (size_t)bg * (kCg * kT));
    float s = 0.f, q = 0.f;
    #pragma unroll 4
    for (int i = 0; i < (kCg * kT / 4) / 256; ++i) {
        float4 v = xp4[tid + i * 256];
        s += v.x + v.y + v.z + v.w;
        q += v.x * v.x + v.y * v.y + v.z * v.z + v.w * v.w;
    }
    #pragma unroll
    for (int off = 32; off > 0; off >>= 1) {
        s += __shfl_down(s, off);
        q += __shfl_down(q, off);
    }
    __shared__ float rs[4], rq[4];
    int wid = tid >> 6, lane = tid & 63;
    if (lane == 0) { rs[wid] = s; rq[wid] = q; }
    __syncthreads();
    if (tid == 0) {
        float S = rs[0] + rs[1] + rs[2] + rs[3];
        float Q = rq[0] + rq[1] + rq[2] + rq[3];
        const float invN = 1.0f / (float)(kCg * kT);
        float mean = S * invN;
        float var  = Q * invN - mean * mean;
        stats[bg * 2 + 0] = mean;
        stats[bg * 2 + 1] = rsqrtf(var + kEps);
    }
}

// ---------------------------------------------------------------------------
// Kernel 2: apply GroupNorm affine + transpose -> normT[b][t][c] bf16.
// ---------------------------------------------------------------------------
__global__ __launch_bounds__(256) void gn_apply_t_kernel(const float* __restrict__ x,
                                                         const float* __restrict__ stats,
                                                         const float* __restrict__ w,
                                                         const float* __restrict__ bias,
                                                         unsigned short* __restrict__ normT) {
    __shared__ float Ls[64][65];
    int t0 = blockIdx.x * 64;
    int c0 = blockIdx.y * 64;
    int b  = blockIdx.z;
    int tid = threadIdx.x;
    #pragma unroll
    for (int p = 0; p < 4; ++p) {
        int idx = tid + p * 256;
        int cl = idx >> 4, t4 = idx & 15;
        int c = c0 + cl;
        int bg = b * kG + (c >> 4);
        float mean = stats[bg * 2 + 0];
        float rstd = stats[bg * 2 + 1];
        float sw = w[c] * rstd;
        float sb = bias[c] - mean * sw;
        float4 v = *(const float4*)&x[((size_t)b * kC + c) * kT + t0 + t4 * 4];
        Ls[t4 * 4 + 0][cl] = v.x * sw + sb;
        Ls[t4 * 4 + 1][cl] = v.y * sw + sb;
        Ls[t4 * 4 + 2][cl] = v.z * sw + sb;
        Ls[t4 * 4 + 3][cl] = v.w * sw + sb;
    }
    __syncthreads();
    {
        int row = tid >> 2, cq = (tid & 3) * 16;
        unsigned tmp[8];
        #pragma unroll
        for (int i = 0; i < 8; ++i)
            tmp[i] = pk2bf(Ls[row][cq + 2 * i], Ls[row][cq + 2 * i + 1]);
        uint4* dst = (uint4*)&normT[((size_t)b * kT + t0 + row) * kC + c0 + cq];
        dst[0] = make_uint4(tmp[0], tmp[1], tmp[2], tmp[3]);
        dst[1] = make_uint4(tmp[4], tmp[5], tmp[6], tmp[7]);
    }
}

// ---------------------------------------------------------------------------
// Kernel 3: qkv GEMM (bf16 MFMA), R9 structure. Epilogue writes q/k/v in
// PRE-FRAGMENTED MFMA operand layouts:
//   q/k: frag[tb=t/32][ks=c/16][hi=(c/8)&1][ln=t&31][e=c&7]
//   v:   frag[sg=s/16][hi=(s/8)&1][c][e=s&7]
// ---------------------------------------------------------------------------
__global__ __launch_bounds__(256) void qkv_gemm_kernel(const unsigned short* __restrict__ wbf,
                                                       const float* __restrict__ qkv_b,
                                                       const unsigned short* __restrict__ normT,
                                                       unsigned short* __restrict__ qTg,
                                                       unsigned short* __restrict__ kTg,
                                                       unsigned short* __restrict__ vCg) {
    constexpr int LDK = 72;
    constexpr int LDV = 136;   // v-staging row length (bf16), 272 B, 16B-aligned
    __shared__ __align__(16) unsigned short As[64 * LDK];
    __shared__ __align__(16) unsigned short Bs[128 * LDK];   // also epilogue staging

    int t0 = blockIdx.x * 128;
    int m0 = blockIdx.y * 64;
    int b  = blockIdx.z;
    const unsigned short* Ab = wbf + (size_t)m0 * kC;
    const unsigned short* Bb = normT + (size_t)b * kT * kC;

    int tid = threadIdx.x;
    int wave = tid >> 6, lane = tid & 63;
    int ln15 = lane & 15, quad = lane >> 4;
    int wm = wave >> 1, wt = wave & 1;

    f32x4 acc[2][4] = {};

    for (int k0 = 0; k0 < kC; k0 += 64) {
        __syncthreads();
        #pragma unroll
        for (int p = 0; p < 2; ++p) {
            int idx = tid + p * 256;
            int row = idx >> 3, seg = idx & 7;
            *(uint4*)&As[row * LDK + seg * 8] =
                *(const uint4*)&Ab[(size_t)row * kC + k0 + seg * 8];
        }
        #pragma unroll
        for (int p = 0; p < 4; ++p) {
            int idx = tid + p * 256;
            int row = idx >> 3, seg = idx & 7;
            *(uint4*)&Bs[row * LDK + seg * 8] =
                *(const uint4*)&Bb[(size_t)(t0 + row) * kC + k0 + seg * 8];
        }
        __syncthreads();
        #pragma unroll
        for (int ks = 0; ks < 2; ++ks) {
            bf16x8 af[2], bf[4];
            #pragma unroll
            for (int i = 0; i < 2; ++i)
                af[i] = *(bf16x8*)&As[(wm * 32 + i * 16 + ln15) * LDK + ks * 32 + quad * 8];
            #pragma unroll
            for (int j = 0; j < 4; ++j)
                bf[j] = *(bf16x8*)&Bs[(wt * 64 + j * 16 + ln15) * LDK + ks * 32 + quad * 8];
            #pragma unroll
            for (int i = 0; i < 2; ++i)
                #pragma unroll
                for (int j = 0; j < 4; ++j)
                    acc[i][j] = __builtin_amdgcn_mfma_f32_16x16x32_bf16(
                        af[i], bf[j], acc[i][j], 0, 0, 0);
        }
    }

    int type = (m0 % 192) / 64;   // 0=q, 1=k, 2=v
    int h = m0 / 192;
    int bh = b * kH + h;
    __syncthreads();   // all MFMA reads of Bs done; reuse Bs as staging
    #pragma unroll
    for (int i = 0; i < 2; ++i) {
        float4 bv = *(const float4*)&qkv_b[m0 + wm * 32 + i * 16 + quad * 4];
        const float* bp = (const float*)&bv;
        #pragma unroll
        for (int j = 0; j < 4; ++j) {
            int tl = wt * 64 + j * 16 + ln15;
            int c = wm * 32 + i * 16 + quad * 4;
            float v0 = acc[i][j][0] + bp[0];
            float v1 = acc[i][j][1] + bp[1];
            float v2 = acc[i][j][2] + bp[2];
            float v3 = acc[i][j][3] + bp[3];
            if (type == 0) {
                v0 *= kQScale; v1 *= kQScale; v2 *= kQScale; v3 *= kQScale;
            }
            if (type != 2) {
                *(uint2*)&Bs[tl * LDK + c] = make_uint2(pk2bf(v0, v1), pk2bf(v2, v3));
            } else {
                Bs[(c + 0) * LDV + tl] = f2bf(v0);
                Bs[(c + 1) * LDV + tl] = f2bf(v1);
                Bs[(c + 2) * LDV + tl] = f2bf(v2);
                Bs[(c + 3) * LDV + tl] = f2bf(v3);
            }
        }
    }
    __syncthreads();
    if (type != 2) {
        unsigned short* base = ((type == 0) ? qTg : kTg) + (size_t)bh * (kT * kCh);
        #pragma unroll
        for (int p = 0; p < 4; ++p) {
            int f = tid + p * 256;
            int ln = f & 31, hif = (f >> 5) & 1, ks = (f >> 6) & 3, tb = f >> 8;
            *(uint4*)&base[((t0 >> 5) + tb) * 2048 + ks * 512 + hif * 256 + ln * 8] =
                *(uint4*)&Bs[(tb * 32 + ln) * LDK + ks * 16 + hif * 8];
        }
    } else {
        unsigned short* base = vCg + (size_t)bh * (kT * kCh);
        #pragma unroll
        for (int p = 0; p < 4; ++p) {
            int f = tid + p * 256;
            int c = f & 63, hif = (f >> 6) & 1, sg = f >> 7;
            *(uint4*)&base[((t0 >> 4) + sg) * 1024 + hif * 512 + c * 8] =
                *(uint4*)&Bs[c * LDV + sg * 16 + hif * 8];
        }
    }
}

// ---------------------------------------------------------------------------
// Kernel 4: SOFTWARE-PIPELINED MFMA flash attention, 32x32x16, no-max exp2.
// R17: unit-coherent re-analysis — MfmaUtil is per-CU-summed, so true
// per-SIMD MFMA occupancy in R16 was ~9%; per-tile wall 2888 cyc vs ~480
// cyc issue work. The survivor hypothesis after R13-R16 falsifications:
// the STRICTLY SERIAL phase chain S->exp2->pack->O per tile, with TLP=2
// the only overlap. Fix (T15): keep two tiles in flight —
//   per step: S(i+1) [MFMA, independent] || softmax(i) [trans/VALU, from
//   S saved last step] -> O(i) [MFMA]; reload freed buffers for i+2/i+3.
// MFMA gets 6 independent chains/step; trans overlaps the S-group; the
// cross-step critical path is broken. Loads placed >=300 cyc from use.
// No sched_barrier pins (they would BLOCK the S||softmax mixing).
// Hand-unrolled x2 with named buffers (static indexing, rule #20).
// Verification: VGPR_Count should rise to ~160-200 (two S-states live).
// C-layout: col t=lane&31, row s=(reg&3)+8*(reg>>2)+4*hi (m74/m101).
// ---------------------------------------------------------------------------
__global__ __launch_bounds__(256, 2) void attn_mfma_kernel(const unsigned short* __restrict__ qTg,
                                                           const unsigned short* __restrict__ kTg,
                                                           const unsigned short* __restrict__ vCg,
                                                           unsigned short* __restrict__ attnT) {
    __shared__ float Ored[2][2][32][64];   // [tc][chunk][acc elem][lane]
    __shared__ float Lred[2][2][64];

    // XCD-chunked work remap: 512 blocks / 8 XCDs -> 64 consecutive work
    // items (= 2 full bh) per XCD. Bijective since 512 % 8 == 0.
    int lid = blockIdx.y * 32 + blockIdx.x;
    int wl  = (lid & 7) * 64 + (lid >> 3);
    int bh  = wl >> 5;
    int t0  = (wl & 31) * 128;
    int b = bh >> 2, h = bh & 3;

    int tid = threadIdx.x;
    int wave = tid >> 6, lane = tid & 63;
    int ln31 = lane & 31, hi = lane >> 5;
    int tc = wave & 1;    // which 64-t span of the block's 128 t
    int sh = wave >> 1;   // which 2048-s half of the KV range

    const unsigned short* qb = qTg + (size_t)bh * (kT * kCh);
    const unsigned short* kb = kTg + (size_t)bh * (kT * kCh);
    const unsigned short* vb = vCg + (size_t)bh * (kT * kCh);

    // Q fragments for the wave's two 32-t chunks (loop-invariant)
    bf16x8 qA[4], qB[4];
    {
        const unsigned short* qp = qb + ((size_t)(t0 >> 5) + tc * 2) * 2048 + hi * 256 + ln31 * 8;
        #pragma unroll
        for (int ks = 0; ks < 4; ++ks) {
            qA[ks] = *(const bf16x8*)(qp + ks * 512);
            qB[ks] = *(const bf16x8*)(qp + 2048 + ks * 512);
        }
    }

    // K tile idx: 2048 shorts per 32-s tile. V: same stride (2 x 16-s groups).
    const unsigned short* kbase = kb + (size_t)sh * 131072 + hi * 256 + ln31 * 8;
    const unsigned short* vbase = vb + (size_t)sh * 131072 + hi * 512 + ln31 * 8;

    float lA = 0.f, lB = 0.f;
    f32x16 oA0 = {}, oA1 = {}, oB0 = {}, oB1 = {};
    union PunP { uint4 u; bf16x8 f; };

    auto loadK = [&](bf16x8* kf, int idx) {
        const unsigned short* kp = kbase + (size_t)idx * 2048;
        kf[0] = *(const bf16x8*)(kp);
        kf[1] = *(const bf16x8*)(kp + 512);
        kf[2] = *(const bf16x8*)(kp + 1024);
        kf[3] = *(const bf16x8*)(kp + 1536);
    };
    auto loadV = [&](bf16x8* vf, int idx) {
        const unsigned short* vp = vbase + (size_t)idx * 2048;
        vf[0] = *(const bf16x8*)(vp);           // ct=0, s-chunk 0
        vf[1] = *(const bf16x8*)(vp + 256);     // ct=1, s-chunk 0
        vf[2] = *(const bf16x8*)(vp + 1024);    // ct=0, s-chunk 1
        vf[3] = *(const bf16x8*)(vp + 1280);    // ct=1, s-chunk 1
    };

    auto sBlock = [&](const bf16x8* kf, f32x16& sA, f32x16& sB) {
        f32x16 a = {}, c = {};
        __builtin_amdgcn_s_setprio(1);
        #pragma unroll
        for (int ks = 0; ks < 4; ++ks) {
            a = __builtin_amdgcn_mfma_f32_32x32x16_bf16(kf[ks], qA[ks], a, 0, 0, 0);
            c = __builtin_amdgcn_mfma_f32_32x32x16_bf16(kf[ks], qB[ks], c, 0, 0, 0);
        }
        __builtin_amdgcn_s_setprio(0);
        sA = a; sB = c;
    };

    auto softmax_pack = [&](const f32x16& s, float& l, bf16x8& f0, bf16x8& f1) {
        unsigned u00, u01, u10, u11, u20, u21, u30, u31;
        {
            float p0 = __builtin_amdgcn_exp2f(s[0]);
            float p1 = __builtin_amdgcn_exp2f(s[1]);
            float p2 = __builtin_amdgcn_exp2f(s[2]);
            float p3 = __builtin_amdgcn_exp2f(s[3]);
            l += (p0 + p1) + (p2 + p3);
            u00 = pk2bf_trunc(p0, p1); u01 = pk2bf_trunc(p2, p3);
        }
        {
            float p0 = __builtin_amdgcn_exp2f(s[4]);
            float p1 = __builtin_amdgcn_exp2f(s[5]);
            float p2 = __builtin_amdgcn_exp2f(s[6]);
            float p3 = __builtin_amdgcn_exp2f(s[7]);
            l += (p0 + p1) + (p2 + p3);
            u10 = pk2bf_trunc(p0, p1); u11 = pk2bf_trunc(p2, p3);
        }
        {
            float p0 = __builtin_amdgcn_exp2f(s[8]);
            float p1 = __builtin_amdgcn_exp2f(s[9]);
            float p2 = __builtin_amdgcn_exp2f(s[10]);
            float p3 = __builtin_amdgcn_exp2f(s[11]);
            l += (p0 + p1) + (p2 + p3);
            u20 = pk2bf_trunc(p0, p1); u21 = pk2bf_trunc(p2, p3);
        }
        {
            float p0 = __builtin_amdgcn_exp2f(s[12]);
            float p1 = __builtin_amdgcn_exp2f(s[13]);
            float p2 = __builtin_amdgcn_exp2f(s[14]);
            float p3 = __builtin_amdgcn_exp2f(s[15]);
            l += (p0 + p1) + (p2 + p3);
            u30 = pk2bf_trunc(p0, p1); u31 = pk2bf_trunc(p2, p3);
        }
        // C-layout -> B-operand, in-register (T12): u[g][w] holds
        // s=(8g+4h+2w,+1); swap(u[g],u[g+1]) yields fragment words for
        // s-chunks [16i+8h, 16i+8h+8).
        pls32(u00, u10); pls32(u01, u11);
        pls32(u20, u30); pls32(u21, u31);
        PunP P0, P1;
        P0.u = make_uint4(u00, u01, u10, u11);
        P1.u = make_uint4(u20, u21, u30, u31);
        f0 = P0.f; f1 = P1.f;
    };

    auto finishTile = [&](const f32x16& sA, const f32x16& sB, const bf16x8* vf) {
        bf16x8 FA0, FA1, FB0, FB1;
        softmax_pack(sA, lA, FA0, FA1);
        softmax_pack(sB, lB, FB0, FB1);
        __builtin_amdgcn_s_setprio(1);
        oA0 = __builtin_amdgcn_mfma_f32_32x32x16_bf16(vf[0], FA0, oA0, 0, 0, 0);
        oA1 = __builtin_amdgcn_mfma_f32_32x32x16_bf16(vf[1], FA0, oA1, 0, 0, 0);
        oB0 = __builtin_amdgcn_mfma_f32_32x32x16_bf16(vf[0], FB0, oB0, 0, 0, 0);
        oB1 = __builtin_amdgcn_mfma_f32_32x32x16_bf16(vf[1], FB0, oB1, 0, 0, 0);
        oA0 = __builtin_amdgcn_mfma_f32_32x32x16_bf16(vf[2], FA1, oA0, 0, 0, 0);
        oA1 = __builtin_amdgcn_mfma_f32_32x32x16_bf16(vf[3], FA1, oA1, 0, 0, 0);
        oB0 = __builtin_amdgcn_mfma_f32_32x32x16_bf16(vf[2], FB1, oB0, 0, 0, 0);
        oB1 = __builtin_amdgcn_mfma_f32_32x32x16_bf16(vf[3], FB1, oB1, 0, 0, 0);
        __builtin_amdgcn_s_setprio(0);
    };

    // Pipeline state: sCA/sCB = S of "current" (not yet softmaxed) tile.
    bf16x8 K0[4], V0[4], K1[4], V1[4];
    f32x16 sCA, sCB, sNA, sNB;

    // Prologue: tiles 0,1 in buffers; S(0) computed.
    loadK(K0, 0); loadV(V0, 0);
    loadK(K1, 1); loadV(V1, 1);
    sBlock(K0, sCA, sCB);                        // S(0)

    #pragma unroll 1
    for (int it = 0; it < 62; it += 2) {
        // EVEN: current = it (sC), next = it+1 (K1); reload K0/V0 <- it+2
        sBlock(K1, sNA, sNB);                    // S(it+1)
        loadK(K0, it + 2);                       // cover: softmax+O below
        finishTile(sCA, sCB, V0);                // softmax(it) + O(it)
        loadV(V0, it + 2);
        sCA = sNA; sCB = sNB;
        // ODD: current = it+1, next = it+2 (K0); reload K1/V1 <- it+3
        sBlock(K0, sNA, sNB);                    // S(it+2)
        loadK(K1, it + 3);
        finishTile(sCA, sCB, V1);                // softmax(it+1) + O(it+1)
        loadV(V1, it + 3);
        sCA = sNA; sCB = sNB;
    }
    // Epilogue: it=62 (sC holds S(62); K1/V1 hold tile 63)
    sBlock(K1, sNA, sNB);                        // S(63)
    finishTile(sCA, sCB, V0);                    // tile 62
    finishTile(sNA, sNB, V1);                    // tile 63

    // ---- combine the two lane-halves' s-subsets
    lA += __shfl_xor(lA, 32);
    lB += __shfl_xor(lB, 32);

    // ---- cross-wave combine of the two s-halves (one-time LDS reduction)
    if (sh == 1) {
        #pragma unroll
        for (int e = 0; e < 16; ++e) {
            Ored[tc][0][e][lane]      = oA0[e];
            Ored[tc][0][16 + e][lane] = oA1[e];
            Ored[tc][1][e][lane]      = oB0[e];
            Ored[tc][1][16 + e][lane] = oB1[e];
        }
        Lred[tc][0][lane] = lA;
        Lred[tc][1][lane] = lB;
    }
    __syncthreads();
    if (sh == 0) {
        #pragma unroll
        for (int e = 0; e < 16; ++e) {
            oA0[e] += Ored[tc][0][e][lane];
            oA1[e] += Ored[tc][0][16 + e][lane];
            oB0[e] += Ored[tc][1][e][lane];
            oB1[e] += Ored[tc][1][16 + e][lane];
        }
        lA += Lred[tc][0][lane];
        lB += Lred[tc][1][lane];
        #pragma unroll
        for (int ch = 0; ch < 2; ++ch) {
            float linv = 1.0f / (ch ? lB : lA);
            int t = t0 + tc * 64 + ch * 32 + ln31;
            #pragma unroll
            for (int ct = 0; ct < 2; ++ct) {
                const f32x16& ao = ch ? (ct ? oB1 : oB0) : (ct ? oA1 : oA0);
                #pragma unroll
                for (int g = 0; g < 4; ++g) {
                    int c = h * kCh + ct * 32 + 8 * g + 4 * hi;
                    float v0 = ao[4 * g + 0] * linv;
                    float v1 = ao[4 * g + 1] * linv;
                    float v2 = ao[4 * g + 2] * linv;
                    float v3 = ao[4 * g + 3] * linv;
                    *(uint2*)&attnT[((size_t)b * kT + t) * kC + c] =
                        make_uint2(pk2bf(v0, v1), pk2bf(v2, v3));
                }
            }
        }
    }
}

// ---------------------------------------------------------------------------
// Kernel 5: proj GEMM (bf16 MFMA, R9 structure) + bias + residual -> fp32.
// ---------------------------------------------------------------------------
__global__ __launch_bounds__(256) void proj_gemm_kernel(const unsigned short* __restrict__ wpbf,
                                                        const float* __restrict__ proj_b,
                                                        const unsigned short* __restrict__ attnT,
                                                        const float* __restrict__ x,
                                                        float* __restrict__ out) {
    constexpr int LDK = 72;
    __shared__ __align__(16) unsigned short As[64 * LDK];
    __shared__ __align__(16) unsigned short Bs[128 * LDK];

    int t0 = blockIdx.x * 128;
    int m0 = blockIdx.y * 64;
    int b  = blockIdx.z;
    const unsigned short* Ab = wpbf + (size_t)m0 * kC;
    const unsigned short* Bb = attnT + (size_t)b * kT * kC;

    int tid = threadIdx.x;
    int wave = tid >> 6, lane = tid & 63;
    int ln15 = lane & 15, quad = lane >> 4;
    int wm = wave >> 1, wt = wave & 1;

    f32x4 acc[2][4] = {};

    for (int k0 = 0; k0 < kC; k0 += 64) {
        __syncthreads();
        #pragma unroll
        for (int p = 0; p < 2; ++p) {
            int idx = tid + p * 256;
            int row = idx >> 3, seg = idx & 7;
            *(uint4*)&As[row * LDK + seg * 8] =
                *(const uint4*)&Ab[(size_t)row * kC + k0 + seg * 8];
        }
        #pragma unroll
        for (int p = 0; p < 4; ++p) {
            int idx = tid + p * 256;
            int row = idx >> 3, seg = idx & 7;
            *(uint4*)&Bs[row * LDK + seg * 8] =
                *(const uint4*)&Bb[(size_t)(t0 + row) * kC + k0 + seg * 8];
        }
        __syncthreads();
        #pragma unroll
        for (int ks = 0; ks < 2; ++ks) {
            bf16x8 af[2], bf[4];
            #pragma unroll
            for (int i = 0; i < 2; ++i)
                af[i] = *(bf16x8*)&As[(wm * 32 + i * 16 + ln15) * LDK + ks * 32 + quad * 8];
            #pragma unroll
            for (int j = 0; j < 4; ++j)
                bf[j] = *(bf16x8*)&Bs[(wt * 64 + j * 16 + ln15) * LDK + ks * 32 + quad * 8];
            #pragma unroll
            for (int i = 0; i < 2; ++i)
                #pragma unroll
                for (int j = 0; j < 4; ++j)
                    acc[i][j] = __builtin_amdgcn_mfma_f32_16x16x32_bf16(
                        af[i], bf[j], acc[i][j], 0, 0, 0);
        }
    }

    #pragma unroll
    for (int i = 0; i < 2; ++i) {
        float4 bv = *(const float4*)&proj_b[m0 + wm * 32 + i * 16 + quad * 4];
        const float* bp = (const float*)&bv;
        #pragma unroll
        for (int j = 0; j < 4; ++j) {
            int t = t0 + wt * 64 + j * 16 + ln15;
            int mbase = m0 + wm * 32 + i * 16 + quad * 4;
            #pragma unroll
            for (int r = 0; r < 4; ++r) {
                size_t off = ((size_t)b * kC + mbase + r) * kT + t;
                out[off] = acc[i][j][r] + bp[r] + x[off];
            }
        }
    }
}

// ---------------------------------------------------------------------------
extern "C" void kernel_launch(void* const* d_in, const int* in_sizes, int n_in,
                              void* d_out, int out_size, void* d_ws, size_t ws_size,
                              hipStream_t stream) {
    const float* x      = (const float*)d_in[0];
    const float* norm_w = (const float*)d_in[1];
    const float* norm_b = (const float*)d_in[2];
    const float* qkv_w  = (const float*)d_in[3];
    const float* qkv_b  = (const float*)d_in[4];
    const float* proj_w = (const float*)d_in[5];
    const float* proj_b = (const float*)d_in[6];
    float* out = (float*)d_out;

    // Workspace: stats fp32[128] | bf16: normT[4.19M] wbf[262144] qT kT vC attnT[4.19M each]
    float* stats = (float*)d_ws;
    unsigned short* wsbf  = (unsigned short*)((float*)d_ws + 128);
    unsigned short* normT = wsbf;
    unsigned short* wbf   = normT + (size_t)kB * kT * kC;
    unsigned short* qTp   = wbf + 262144;
    unsigned short* kTp   = qTp + (size_t)kB * kH * kT * kCh;
    unsigned short* vCp   = kTp + (size_t)kB * kH * kT * kCh;
    unsigned short* attnT = vCp + (size_t)kB * kH * kT * kCh;
    unsigned short* wpbf  = wbf + 196608;

    prep_kernel<<<192, 256, 0, stream>>>(x, stats, qkv_w, proj_w, wbf);
    gn_apply_t_kernel<<<dim3(kT / 64, kC / 64, kB), 256, 0, stream>>>(
        x, stats, norm_w, norm_b, normT);
    qkv_gemm_kernel<<<dim3(kT / 128, 12, kB), 256, 0, stream>>>(
        wbf, qkv_b, normT, qTp, kTp, vCp);
    attn_mfma_kernel<<<dim3(kT / 128, kB * kH), 256, 0, stream>>>(qTp, kTp, vCp, attnT);
    proj_gemm_kernel<<<dim3(kT / 128, kC / 64, kB), 256, 0, stream>>>(
        wpbf, proj_b, attnT, x, out);
}

// Round 7
// 198.139 us; speedup vs baseline: 1.0096x; 1.0096x over previous
//
#include <hip/hip_runtime.h>

// Problem constants (B=4, C=256, H=W=64 -> T=4096)
constexpr int kB  = 4;
constexpr int kC  = 256;
constexpr int kT  = 4096;
constexpr int kG  = 16;
constexpr int kCg = kC / kG;   // 16 channels per group
constexpr int kH  = 4;         // heads
constexpr int kCh = kC / kH;   // 64 channels per head
constexpr float kEps = 1e-5f;
// q scale: 1/8 (=scale^2) folded with log2(e) for exp2-domain softmax
constexpr float kQScale = 0.125f * 1.4426950408889634f;

typedef short bf16x8 __attribute__((ext_vector_type(8)));
typedef float f32x4  __attribute__((ext_vector_type(4)));
typedef float f32x16 __attribute__((ext_vector_type(16)));

union PunP { uint4 u; bf16x8 f; };

__device__ inline unsigned short f2bf(float f) {
    union { float f; unsigned u; } v; v.f = f;
    unsigned r = v.u + 0x7fffu + ((v.u >> 16) & 1u);   // RNE
    return (unsigned short)(r >> 16);
}
__device__ inline unsigned pk2bf(float a, float b) {
    return (unsigned)f2bf(a) | ((unsigned)f2bf(b) << 16);
}
// truncating pack of two fp32 -> bf16x2 in ONE v_perm_b32 (high halves)
__device__ inline unsigned pk2bf_trunc(float a, float b) {
    return __builtin_amdgcn_perm(__float_as_uint(b), __float_as_uint(a), 0x07060302u);
}
// v_permlane32_swap_b32: a[32:63] <-> b[0:31].
__device__ inline void pls32(unsigned& a, unsigned& b) {
    __asm__("v_permlane32_swap_b32 %0, %1" : "+v"(a), "+v"(b));
}

// ---------------------------------------------------------------------------
// Kernel 1: GroupNorm statistics (blocks 0..63) + weight fp32->bf16 convert
// (blocks 64..191) fused into one launch.
// ---------------------------------------------------------------------------
__global__ __launch_bounds__(256) void prep_kernel(const float* __restrict__ x,
                                                   float* __restrict__ stats,
                                                   const float* __restrict__ qkv_w,
                                                   const float* __restrict__ proj_w,
                                                   unsigned short* __restrict__ wbf) {
    int tid = threadIdx.x;
    if (blockIdx.x >= 64) {
        int gid = (blockIdx.x - 64) * 256 + tid;
        for (int i = gid; i < 65536; i += 128 * 256) {
            float4 v = (i < 49152) ? ((const float4*)qkv_w)[i]
                                   : ((const float4*)proj_w)[i - 49152];
            *(uint2*)&wbf[(size_t)i * 4] = make_uint2(pk2bf(v.x, v.y), pk2bf(v.z, v.w));
        }
        return;
    }
    int bg = blockIdx.x;
    const float4* xp4 = (const float4*)(x + (size_t)bg * (kCg * kT));
    float s = 0.f, q = 0.f;
    #pragma unroll 4
    for (int i = 0; i < (kCg * kT / 4) / 256; ++i) {
        float4 v = xp4[tid + i * 256];
        s += v.x + v.y + v.z + v.w;
        q += v.x * v.x + v.y * v.y + v.z * v.z + v.w * v.w;
    }
    #pragma unroll
    for (int off = 32; off > 0; off >>= 1) {
        s += __shfl_down(s, off);
        q += __shfl_down(q, off);
    }
    __shared__ float rs[4], rq[4];
    int wid = tid >> 6, lane = tid & 63;
    if (lane == 0) { rs[wid] = s; rq[wid] = q; }
    __syncthreads();
    if (tid == 0) {
        float S = rs[0] + rs[1] + rs[2] + rs[3];
        float Q = rq[0] + rq[1] + rq[2] + rq[3];
        const float invN = 1.0f / (float)(kCg * kT);
        float mean = S * invN;
        float var  = Q * invN - mean * mean;
        stats[bg * 2 + 0] = mean;
        stats[bg * 2 + 1] = rsqrtf(var + kEps);
    }
}

// ---------------------------------------------------------------------------
// Kernel 2: apply GroupNorm affine + transpose -> normT[b][t][c] bf16.
// ---------------------------------------------------------------------------
__global__ __launch_bounds__(256) void gn_apply_t_kernel(const float* __restrict__ x,
                                                         const float* __restrict__ stats,
                                                         const float* __restrict__ w,
                                                         const float* __restrict__ bias,
                                                         unsigned short* __restrict__ normT) {
    __shared__ float Ls[64][65];
    int t0 = blockIdx.x * 64;
    int c0 = blockIdx.y * 64;
    int b  = blockIdx.z;
    int tid = threadIdx.x;
    #pragma unroll
    for (int p = 0; p < 4; ++p) {
        int idx = tid + p * 256;
        int cl = idx >> 4, t4 = idx & 15;
        int c = c0 + cl;
        int bg = b * kG + (c >> 4);
        float mean = stats[bg * 2 + 0];
        float rstd = stats[bg * 2 + 1];
        float sw = w[c] * rstd;
        float sb = bias[c] - mean * sw;
        float4 v = *(const float4*)&x[((size_t)b * kC + c) * kT + t0 + t4 * 4];
        Ls[t4 * 4 + 0][cl] = v.x * sw + sb;
        Ls[t4 * 4 + 1][cl] = v.y * sw + sb;
        Ls[t4 * 4 + 2][cl] = v.z * sw + sb;
        Ls[t4 * 4 + 3][cl] = v.w * sw + sb;
    }
    __syncthreads();
    {
        int row = tid >> 2, cq = (tid & 3) * 16;
        unsigned tmp[8];
        #pragma unroll
        for (int i = 0; i < 8; ++i)
            tmp[i] = pk2bf(Ls[row][cq + 2 * i], Ls[row][cq + 2 * i + 1]);
        uint4* dst = (uint4*)&normT[((size_t)b * kT + t0 + row) * kC + c0 + cq];
        dst[0] = make_uint4(tmp[0], tmp[1], tmp[2], tmp[3]);
        dst[1] = make_uint4(tmp[4], tmp[5], tmp[6], tmp[7]);
    }
}

// ---------------------------------------------------------------------------
// Kernel 3: qkv GEMM (bf16 MFMA), R9 structure. Epilogue writes q/k/v in
// PRE-FRAGMENTED MFMA operand layouts:
//   q/k: frag[tb=t/32][ks=c/16][hi=(c/8)&1][ln=t&31][e=c&7]
//   v:   frag[sg=s/16][hi=(s/8)&1][c][e=s&7]
// ---------------------------------------------------------------------------
__global__ __launch_bounds__(256) void qkv_gemm_kernel(const unsigned short* __restrict__ wbf,
                                                       const float* __restrict__ qkv_b,
                                                       const unsigned short* __restrict__ normT,
                                                       unsigned short* __restrict__ qTg,
                                                       unsigned short* __restrict__ kTg,
                                                       unsigned short* __restrict__ vCg) {
    constexpr int LDK = 72;
    constexpr int LDV = 136;   // v-staging row length (bf16), 272 B, 16B-aligned
    __shared__ __align__(16) unsigned short As[64 * LDK];
    __shared__ __align__(16) unsigned short Bs[128 * LDK];   // also epilogue staging

    int t0 = blockIdx.x * 128;
    int m0 = blockIdx.y * 64;
    int b  = blockIdx.z;
    const unsigned short* Ab = wbf + (size_t)m0 * kC;
    const unsigned short* Bb = normT + (size_t)b * kT * kC;

    int tid = threadIdx.x;
    int wave = tid >> 6, lane = tid & 63;
    int ln15 = lane & 15, quad = lane >> 4;
    int wm = wave >> 1, wt = wave & 1;

    f32x4 acc[2][4] = {};

    for (int k0 = 0; k0 < kC; k0 += 64) {
        __syncthreads();
        #pragma unroll
        for (int p = 0; p < 2; ++p) {
            int idx = tid + p * 256;
            int row = idx >> 3, seg = idx & 7;
            *(uint4*)&As[row * LDK + seg * 8] =
                *(const uint4*)&Ab[(size_t)row * kC + k0 + seg * 8];
        }
        #pragma unroll
        for (int p = 0; p < 4; ++p) {
            int idx = tid + p * 256;
            int row = idx >> 3, seg = idx & 7;
            *(uint4*)&Bs[row * LDK + seg * 8] =
                *(const uint4*)&Bb[(size_t)(t0 + row) * kC + k0 + seg * 8];
        }
        __syncthreads();
        #pragma unroll
        for (int ks = 0; ks < 2; ++ks) {
            bf16x8 af[2], bf[4];
            #pragma unroll
            for (int i = 0; i < 2; ++i)
                af[i] = *(bf16x8*)&As[(wm * 32 + i * 16 + ln15) * LDK + ks * 32 + quad * 8];
            #pragma unroll
            for (int j = 0; j < 4; ++j)
                bf[j] = *(bf16x8*)&Bs[(wt * 64 + j * 16 + ln15) * LDK + ks * 32 + quad * 8];
            #pragma unroll
            for (int i = 0; i < 2; ++i)
                #pragma unroll
                for (int j = 0; j < 4; ++j)
                    acc[i][j] = __builtin_amdgcn_mfma_f32_16x16x32_bf16(
                        af[i], bf[j], acc[i][j], 0, 0, 0);
        }
    }

    int type = (m0 % 192) / 64;   // 0=q, 1=k, 2=v
    int h = m0 / 192;
    int bh = b * kH + h;
    __syncthreads();   // all MFMA reads of Bs done; reuse Bs as staging
    #pragma unroll
    for (int i = 0; i < 2; ++i) {
        float4 bv = *(const float4*)&qkv_b[m0 + wm * 32 + i * 16 + quad * 4];
        const float* bp = (const float*)&bv;
        #pragma unroll
        for (int j = 0; j < 4; ++j) {
            int tl = wt * 64 + j * 16 + ln15;
            int c = wm * 32 + i * 16 + quad * 4;
            float v0 = acc[i][j][0] + bp[0];
            float v1 = acc[i][j][1] + bp[1];
            float v2 = acc[i][j][2] + bp[2];
            float v3 = acc[i][j][3] + bp[3];
            if (type == 0) {
                v0 *= kQScale; v1 *= kQScale; v2 *= kQScale; v3 *= kQScale;
            }
            if (type != 2) {
                *(uint2*)&Bs[tl * LDK + c] = make_uint2(pk2bf(v0, v1), pk2bf(v2, v3));
            } else {
                Bs[(c + 0) * LDV + tl] = f2bf(v0);
                Bs[(c + 1) * LDV + tl] = f2bf(v1);
                Bs[(c + 2) * LDV + tl] = f2bf(v2);
                Bs[(c + 3) * LDV + tl] = f2bf(v3);
            }
        }
    }
    __syncthreads();
    if (type != 2) {
        unsigned short* base = ((type == 0) ? qTg : kTg) + (size_t)bh * (kT * kCh);
        #pragma unroll
        for (int p = 0; p < 4; ++p) {
            int f = tid + p * 256;
            int ln = f & 31, hif = (f >> 5) & 1, ks = (f >> 6) & 3, tb = f >> 8;
            *(uint4*)&base[((t0 >> 5) + tb) * 2048 + ks * 512 + hif * 256 + ln * 8] =
                *(uint4*)&Bs[(tb * 32 + ln) * LDK + ks * 16 + hif * 8];
        }
    } else {
        unsigned short* base = vCg + (size_t)bh * (kT * kCh);
        #pragma unroll
        for (int p = 0; p < 4; ++p) {
            int f = tid + p * 256;
            int c = f & 63, hif = (f >> 6) & 1, sg = f >> 7;
            *(uint4*)&base[((t0 >> 4) + sg) * 1024 + hif * 512 + c * 8] =
                *(uint4*)&Bs[c * LDV + sg * 16 + hif * 8];
        }
    }
}

// ---------------------------------------------------------------------------
// Kernel 4: 1-WAVE/SIMD MFMA flash attention, 32x32x16, no-max exp2.
// R19: R18's 4-deep fused rewrite NaN'd (stale-buffer epilogue + too many
// simultaneous changes) -> discarded. This round changes ONE variable on
// the PROVEN R17 pipeline (passed 3 rounds): execution configuration.
// Grid 256 = 1 block/CU, __launch_bounds__(256,1) = 1 wave/SIMD with the
// full 512-reg unified budget. Each wave owns 64 t over the FULL s-range
// (128 tiles); no cross-wave reduction, no LDS. Theory under test (from
// R17's VGPR_Count=128=exactly-the-cap): at 2 waves/SIMD the allocator
// must serialize pipeline phases to fit 256 regs, and co-resident waves
// phase-lock; with 512 regs the S(i+1) MFMA || softmax(i) || O(i)
// pipeline can actually materialize.
// Pre-commit: attn >= 70us => theory falsified, pivot to other kernels.
// C-layout: col t=lane&31, row s=(reg&3)+8*(reg>>2)+4*hi (m74/m101).
// ---------------------------------------------------------------------------
__global__ __launch_bounds__(256, 1) void attn_mfma_kernel(const unsigned short* __restrict__ qTg,
                                                           const unsigned short* __restrict__ kTg,
                                                           const unsigned short* __restrict__ vCg,
                                                           unsigned short* __restrict__ attnT) {
    // XCD-chunked work remap: 256 blocks / 8 XCDs -> 32 consecutive work
    // items (= 2 full bh) per XCD. Bijective since 256 % 8 == 0.
    int lid = blockIdx.x;
    int wl  = (lid & 7) * 32 + (lid >> 3);
    int bh  = wl >> 4;
    int t0  = (wl & 15) * 256;
    int b = bh >> 2, h = bh & 3;

    int tid = threadIdx.x;
    int wave = tid >> 6, lane = tid & 63;
    int ln31 = lane & 31, hi = lane >> 5;

    const unsigned short* qb = qTg + (size_t)bh * (kT * kCh);
    const unsigned short* kb = kTg + (size_t)bh * (kT * kCh);
    const unsigned short* vb = vCg + (size_t)bh * (kT * kCh);

    // Q fragments for the wave's two 32-t chunks (loop-invariant).
    // Wave's t-span = t0 + wave*64.
    bf16x8 qA[4], qB[4];
    {
        const unsigned short* qp = qb + ((size_t)(t0 >> 5) + wave * 2) * 2048 + hi * 256 + ln31 * 8;
        #pragma unroll
        for (int ks = 0; ks < 4; ++ks) {
            qA[ks] = *(const bf16x8*)(qp + ks * 512);
            qB[ks] = *(const bf16x8*)(qp + 2048 + ks * 512);
        }
    }

    // Full s-range: 128 tiles of 32 s, 2048 shorts per tile.
    const unsigned short* kbase = kb + hi * 256 + ln31 * 8;
    const unsigned short* vbase = vb + hi * 512 + ln31 * 8;

    float lA = 0.f, lB = 0.f;
    f32x16 oA0 = {}, oA1 = {}, oB0 = {}, oB1 = {};

    auto loadK = [&](bf16x8* kf, int idx) {
        const unsigned short* kp = kbase + (size_t)idx * 2048;
        kf[0] = *(const bf16x8*)(kp);
        kf[1] = *(const bf16x8*)(kp + 512);
        kf[2] = *(const bf16x8*)(kp + 1024);
        kf[3] = *(const bf16x8*)(kp + 1536);
    };
    auto loadV = [&](bf16x8* vf, int idx) {
        const unsigned short* vp = vbase + (size_t)idx * 2048;
        vf[0] = *(const bf16x8*)(vp);           // ct=0, s-chunk 0
        vf[1] = *(const bf16x8*)(vp + 256);     // ct=1, s-chunk 0
        vf[2] = *(const bf16x8*)(vp + 1024);    // ct=0, s-chunk 1
        vf[3] = *(const bf16x8*)(vp + 1280);    // ct=1, s-chunk 1
    };

    auto sBlock = [&](const bf16x8* kf, f32x16& sA, f32x16& sB) {
        f32x16 a = {}, c = {};
        #pragma unroll
        for (int ks = 0; ks < 4; ++ks) {
            a = __builtin_amdgcn_mfma_f32_32x32x16_bf16(kf[ks], qA[ks], a, 0, 0, 0);
            c = __builtin_amdgcn_mfma_f32_32x32x16_bf16(kf[ks], qB[ks], c, 0, 0, 0);
        }
        sA = a; sB = c;
    };

    auto softmax_pack = [&](const f32x16& s, float& l, bf16x8& f0, bf16x8& f1) {
        unsigned u00, u01, u10, u11, u20, u21, u30, u31;
        {
            float p0 = __builtin_amdgcn_exp2f(s[0]);
            float p1 = __builtin_amdgcn_exp2f(s[1]);
            float p2 = __builtin_amdgcn_exp2f(s[2]);
            float p3 = __builtin_amdgcn_exp2f(s[3]);
            l += (p0 + p1) + (p2 + p3);
            u00 = pk2bf_trunc(p0, p1); u01 = pk2bf_trunc(p2, p3);
        }
        {
            float p0 = __builtin_amdgcn_exp2f(s[4]);
            float p1 = __builtin_amdgcn_exp2f(s[5]);
            float p2 = __builtin_amdgcn_exp2f(s[6]);
            float p3 = __builtin_amdgcn_exp2f(s[7]);
            l += (p0 + p1) + (p2 + p3);
            u10 = pk2bf_trunc(p0, p1); u11 = pk2bf_trunc(p2, p3);
        }
        {
            float p0 = __builtin_amdgcn_exp2f(s[8]);
            float p1 = __builtin_amdgcn_exp2f(s[9]);
            float p2 = __builtin_amdgcn_exp2f(s[10]);
            float p3 = __builtin_amdgcn_exp2f(s[11]);
            l += (p0 + p1) + (p2 + p3);
            u20 = pk2bf_trunc(p0, p1); u21 = pk2bf_trunc(p2, p3);
        }
        {
            float p0 = __builtin_amdgcn_exp2f(s[12]);
            float p1 = __builtin_amdgcn_exp2f(s[13]);
            float p2 = __builtin_amdgcn_exp2f(s[14]);
            float p3 = __builtin_amdgcn_exp2f(s[15]);
            l += (p0 + p1) + (p2 + p3);
            u30 = pk2bf_trunc(p0, p1); u31 = pk2bf_trunc(p2, p3);
        }
        // C-layout -> B-operand, in-register (T12): u[g][w] holds
        // s=(8g+4h+2w,+1); swap(u[g],u[g+1]) yields fragment words for
        // s-chunks [16i+8h, 16i+8h+8).
        pls32(u00, u10); pls32(u01, u11);
        pls32(u20, u30); pls32(u21, u31);
        PunP P0, P1;
        P0.u = make_uint4(u00, u01, u10, u11);
        P1.u = make_uint4(u20, u21, u30, u31);
        f0 = P0.f; f1 = P1.f;
    };

    auto finishTile = [&](const f32x16& sA, const f32x16& sB, const bf16x8* vf) {
        bf16x8 FA0, FA1, FB0, FB1;
        softmax_pack(sA, lA, FA0, FA1);
        softmax_pack(sB, lB, FB0, FB1);
        oA0 = __builtin_amdgcn_mfma_f32_32x32x16_bf16(vf[0], FA0, oA0, 0, 0, 0);
        oA1 = __builtin_amdgcn_mfma_f32_32x32x16_bf16(vf[1], FA0, oA1, 0, 0, 0);
        oB0 = __builtin_amdgcn_mfma_f32_32x32x16_bf16(vf[0], FB0, oB0, 0, 0, 0);
        oB1 = __builtin_amdgcn_mfma_f32_32x32x16_bf16(vf[1], FB0, oB1, 0, 0, 0);
        oA0 = __builtin_amdgcn_mfma_f32_32x32x16_bf16(vf[2], FA1, oA0, 0, 0, 0);
        oA1 = __builtin_amdgcn_mfma_f32_32x32x16_bf16(vf[3], FA1, oA1, 0, 0, 0);
        oB0 = __builtin_amdgcn_mfma_f32_32x32x16_bf16(vf[2], FB1, oB0, 0, 0, 0);
        oB1 = __builtin_amdgcn_mfma_f32_32x32x16_bf16(vf[3], FB1, oB1, 0, 0, 0);
    };

    // Pipeline state: sCA/sCB = S of "current" (not yet softmaxed) tile.
    bf16x8 K0[4], V0[4], K1[4], V1[4];
    f32x16 sCA, sCB, sNA, sNB;

    // Prologue: tiles 0,1 in buffers; S(0) computed.
    loadK(K0, 0); loadV(V0, 0);
    loadK(K1, 1); loadV(V1, 1);
    sBlock(K0, sCA, sCB);                        // S(0)

    #pragma unroll 1
    for (int it = 0; it < 126; it += 2) {
        // EVEN: current = it (sC), next = it+1 (K1); reload K0/V0 <- it+2
        sBlock(K1, sNA, sNB);                    // S(it+1)
        loadK(K0, it + 2);                       // cover: softmax+O below
        finishTile(sCA, sCB, V0);                // softmax(it) + O(it)
        loadV(V0, it + 2);
        sCA = sNA; sCB = sNB;
        // ODD: current = it+1, next = it+2 (K0); reload K1/V1 <- it+3
        sBlock(K0, sNA, sNB);                    // S(it+2)
        loadK(K1, it + 3);
        finishTile(sCA, sCB, V1);                // softmax(it+1) + O(it+1)
        loadV(V1, it + 3);
        sCA = sNA; sCB = sNB;
    }
    // Epilogue: after it=124 body, sC = S(126); K0/V0 = tile 126, K1/V1 = 127.
    sBlock(K1, sNA, sNB);                        // S(127)
    finishTile(sCA, sCB, V0);                    // tile 126
    finishTile(sNA, sNB, V1);                    // tile 127

    // ---- combine the two lane-halves' s-subsets
    lA += __shfl_xor(lA, 32);
    lB += __shfl_xor(lB, 32);

    // ---- write out (each wave owns its full 64-t span; no reduction)
    #pragma unroll
    for (int ch = 0; ch < 2; ++ch) {
        float linv = 1.0f / (ch ? lB : lA);
        int t = t0 + wave * 64 + ch * 32 + ln31;
        #pragma unroll
        for (int ct = 0; ct < 2; ++ct) {
            const f32x16& ao = ch ? (ct ? oB1 : oB0) : (ct ? oA1 : oA0);
            #pragma unroll
            for (int g = 0; g < 4; ++g) {
                int c = h * kCh + ct * 32 + 8 * g + 4 * hi;
                float v0 = ao[4 * g + 0] * linv;
                float v1 = ao[4 * g + 1] * linv;
                float v2 = ao[4 * g + 2] * linv;
                float v3 = ao[4 * g + 3] * linv;
                *(uint2*)&attnT[((size_t)b * kT + t) * kC + c] =
                    make_uint2(pk2bf(v0, v1), pk2bf(v2, v3));
            }
        }
    }
}

// ---------------------------------------------------------------------------
// Kernel 5: proj GEMM (bf16 MFMA, R9 structure) + bias + residual -> fp32.
// ---------------------------------------------------------------------------
__global__ __launch_bounds__(256) void proj_gemm_kernel(const unsigned short* __restrict__ wpbf,
                                                        const float* __restrict__ proj_b,
                                                        const unsigned short* __restrict__ attnT,
                                                        const float* __restrict__ x,
                                                        float* __restrict__ out) {
    constexpr int LDK = 72;
    __shared__ __align__(16) unsigned short As[64 * LDK];
    __shared__ __align__(16) unsigned short Bs[128 * LDK];

    int t0 = blockIdx.x * 128;
    int m0 = blockIdx.y * 64;
    int b  = blockIdx.z;
    const unsigned short* Ab = wpbf + (size_t)m0 * kC;
    const unsigned short* Bb = attnT + (size_t)b * kT * kC;

    int tid = threadIdx.x;
    int wave = tid >> 6, lane = tid & 63;
    int ln15 = lane & 15, quad = lane >> 4;
    int wm = wave >> 1, wt = wave & 1;

    f32x4 acc[2][4] = {};

    for (int k0 = 0; k0 < kC; k0 += 64) {
        __syncthreads();
        #pragma unroll
        for (int p = 0; p < 2; ++p) {
            int idx = tid + p * 256;
            int row = idx >> 3, seg = idx & 7;
            *(uint4*)&As[row * LDK + seg * 8] =
                *(const uint4*)&Ab[(size_t)row * kC + k0 + seg * 8];
        }
        #pragma unroll
        for (int p = 0; p < 4; ++p) {
            int idx = tid + p * 256;
            int row = idx >> 3, seg = idx & 7;
            *(uint4*)&Bs[row * LDK + seg * 8] =
                *(const uint4*)&Bb[(size_t)(t0 + row) * kC + k0 + seg * 8];
        }
        __syncthreads();
        #pragma unroll
        for (int ks = 0; ks < 2; ++ks) {
            bf16x8 af[2], bf[4];
            #pragma unroll
            for (int i = 0; i < 2; ++i)
                af[i] = *(bf16x8*)&As[(wm * 32 + i * 16 + ln15) * LDK + ks * 32 + quad * 8];
            #pragma unroll
            for (int j = 0; j < 4; ++j)
                bf[j] = *(bf16x8*)&Bs[(wt * 64 + j * 16 + ln15) * LDK + ks * 32 + quad * 8];
            #pragma unroll
            for (int i = 0; i < 2; ++i)
                #pragma unroll
                for (int j = 0; j < 4; ++j)
                    acc[i][j] = __builtin_amdgcn_mfma_f32_16x16x32_bf16(
                        af[i], bf[j], acc[i][j], 0, 0, 0);
        }
    }

    #pragma unroll
    for (int i = 0; i < 2; ++i) {
        float4 bv = *(const float4*)&proj_b[m0 + wm * 32 + i * 16 + quad * 4];
        const float* bp = (const float*)&bv;
        #pragma unroll
        for (int j = 0; j < 4; ++j) {
            int t = t0 + wt * 64 + j * 16 + ln15;
            int mbase = m0 + wm * 32 + i * 16 + quad * 4;
            #pragma unroll
            for (int r = 0; r < 4; ++r) {
                size_t off = ((size_t)b * kC + mbase + r) * kT + t;
                out[off] = acc[i][j][r] + bp[r] + x[off];
            }
        }
    }
}

// ---------------------------------------------------------------------------
extern "C" void kernel_launch(void* const* d_in, const int* in_sizes, int n_in,
                              void* d_out, int out_size, void* d_ws, size_t ws_size,
                              hipStream_t stream) {
    const float* x      = (const float*)d_in[0];
    const float* norm_w = (const float*)d_in[1];
    const float* norm_b = (const float*)d_in[2];
    const float* qkv_w  = (const float*)d_in[3];
    const float* qkv_b  = (const float*)d_in[4];
    const float* proj_w = (const float*)d_in[5];
    const float* proj_b = (const float*)d_in[6];
    float* out = (float*)d_out;

    // Workspace: stats fp32[128] | bf16: normT[4.19M] wbf[262144] qT kT vC attnT[4.19M each]
    float* stats = (float*)d_ws;
    unsigned short* wsbf  = (unsigned short*)((float*)d_ws + 128);
    unsigned short* normT = wsbf;
    unsigned short* wbf   = normT + (size_t)kB * kT * kC;
    unsigned short* qTp   = wbf + 262144;
    unsigned short* kTp   = qTp + (size_t)kB * kH * kT * kCh;
    unsigned short* vCp   = kTp + (size_t)kB * kH * kT * kCh;
    unsigned short* attnT = vCp + (size_t)kB * kH * kT * kCh;
    unsigned short* wpbf  = wbf + 196608;

    prep_kernel<<<192, 256, 0, stream>>>(x, stats, qkv_w, proj_w, wbf);
    gn_apply_t_kernel<<<dim3(kT / 64, kC / 64, kB), 256, 0, stream>>>(
        x, stats, norm_w, norm_b, normT);
    qkv_gemm_kernel<<<dim3(kT / 128, 12, kB), 256, 0, stream>>>(
        wbf, qkv_b, normT, qTp, kTp, vCp);
    attn_mfma_kernel<<<256, 256, 0, stream>>>(qTp, kTp, vCp, attnT);
    proj_gemm_kernel<<<dim3(kT / 128, kC / 64, kB), 256, 0, stream>>>(
        wpbf, proj_b, attnT, x, out);
}

// Round 8
// 184.944 us; speedup vs baseline: 1.0817x; 1.0713x over previous
//
#include <hip/hip_runtime.h>

// Problem constants (B=4, C=256, H=W=64 -> T=4096)
constexpr int kB  = 4;
constexpr int kC  = 256;
constexpr int kT  = 4096;
constexpr int kG  = 16;
constexpr int kCg = kC / kG;   // 16 channels per group
constexpr int kH  = 4;         // heads
constexpr int kCh = kC / kH;   // 64 channels per head
constexpr float kEps = 1e-5f;
// q scale: 1/8 (=scale^2) folded with log2(e) for exp2-domain softmax
constexpr float kQScale = 0.125f * 1.4426950408889634f;

typedef short bf16x8 __attribute__((ext_vector_type(8)));
typedef float f32x4  __attribute__((ext_vector_type(4)));
typedef float f32x16 __attribute__((ext_vector_type(16)));

union PunP { uint4 u; bf16x8 f; };

__device__ inline unsigned short f2bf(float f) {
    union { float f; unsigned u; } v; v.f = f;
    unsigned r = v.u + 0x7fffu + ((v.u >> 16) & 1u);   // RNE
    return (unsigned short)(r >> 16);
}
__device__ inline unsigned pk2bf(float a, float b) {
    return (unsigned)f2bf(a) | ((unsigned)f2bf(b) << 16);
}
// truncating pack of two fp32 -> bf16x2 in ONE v_perm_b32 (high halves)
__device__ inline unsigned pk2bf_trunc(float a, float b) {
    return __builtin_amdgcn_perm(__float_as_uint(b), __float_as_uint(a), 0x07060302u);
}
// v_permlane32_swap_b32: a[32:63] <-> b[0:31].
__device__ inline void pls32(unsigned& a, unsigned& b) {
    __asm__("v_permlane32_swap_b32 %0, %1" : "+v"(a), "+v"(b));
}

// ---------------------------------------------------------------------------
// Kernel 1: GroupNorm statistics + weight fp32->bf16 convert.
// R20: the stats read (16 MB) was spread over only 64 blocks (1/4 of the
// CUs, ~256 KB serial stream each ~8-10us). Now 256 blocks (4 per group)
// accumulate raw (sum, sumsq) into stats[] via fp32 atomicAdd (stats is
// zeroed by hipMemsetAsync each launch); gn_apply computes mean/rstd from
// the raw sums. Weight convert unchanged on blocks 256..383.
// ---------------------------------------------------------------------------
__global__ __launch_bounds__(256) void prep_kernel(const float* __restrict__ x,
                                                   float* __restrict__ stats,
                                                   const float* __restrict__ qkv_w,
                                                   const float* __restrict__ proj_w,
                                                   unsigned short* __restrict__ wbf) {
    int tid = threadIdx.x;
    if (blockIdx.x >= 256) {
        int gid = (blockIdx.x - 256) * 256 + tid;
        for (int i = gid; i < 65536; i += 128 * 256) {
            float4 v = (i < 49152) ? ((const float4*)qkv_w)[i]
                                   : ((const float4*)proj_w)[i - 49152];
            *(uint2*)&wbf[(size_t)i * 4] = make_uint2(pk2bf(v.x, v.y), pk2bf(v.z, v.w));
        }
        return;
    }
    int bg = blockIdx.x >> 2, part = blockIdx.x & 3;
    // Each block reads 1/4 of one group's 65536 floats: 4096 float4s.
    const float4* xp4 = (const float4*)(x + (size_t)bg * (kCg * kT)) + part * 4096;
    float s = 0.f, q = 0.f;
    #pragma unroll 4
    for (int i = 0; i < 16; ++i) {
        float4 v = xp4[tid + i * 256];
        s += v.x + v.y + v.z + v.w;
        q += v.x * v.x + v.y * v.y + v.z * v.z + v.w * v.w;
    }
    #pragma unroll
    for (int off = 32; off > 0; off >>= 1) {
        s += __shfl_down(s, off);
        q += __shfl_down(q, off);
    }
    __shared__ float rs[4], rq[4];
    int wid = tid >> 6, lane = tid & 63;
    if (lane == 0) { rs[wid] = s; rq[wid] = q; }
    __syncthreads();
    if (tid == 0) {
        float S = rs[0] + rs[1] + rs[2] + rs[3];
        float Q = rq[0] + rq[1] + rq[2] + rq[3];
        atomicAdd(&stats[bg * 2 + 0], S);
        atomicAdd(&stats[bg * 2 + 1], Q);
    }
}

// ---------------------------------------------------------------------------
// Kernel 2: apply GroupNorm affine + transpose -> normT[b][t][c] bf16.
// stats[] now holds raw (sum, sumsq); mean/rstd computed here (cheap).
// ---------------------------------------------------------------------------
__global__ __launch_bounds__(256) void gn_apply_t_kernel(const float* __restrict__ x,
                                                         const float* __restrict__ stats,
                                                         const float* __restrict__ w,
                                                         const float* __restrict__ bias,
                                                         unsigned short* __restrict__ normT) {
    __shared__ float Ls[64][65];
    int t0 = blockIdx.x * 64;
    int c0 = blockIdx.y * 64;
    int b  = blockIdx.z;
    int tid = threadIdx.x;
    const float invN = 1.0f / (float)(kCg * kT);
    #pragma unroll
    for (int p = 0; p < 4; ++p) {
        int idx = tid + p * 256;
        int cl = idx >> 4, t4 = idx & 15;
        int c = c0 + cl;
        int bg = b * kG + (c >> 4);
        float S = stats[bg * 2 + 0];
        float Q = stats[bg * 2 + 1];
        float mean = S * invN;
        float rstd = rsqrtf(Q * invN - mean * mean + kEps);
        float sw = w[c] * rstd;
        float sb = bias[c] - mean * sw;
        float4 v = *(const float4*)&x[((size_t)b * kC + c) * kT + t0 + t4 * 4];
        Ls[t4 * 4 + 0][cl] = v.x * sw + sb;
        Ls[t4 * 4 + 1][cl] = v.y * sw + sb;
        Ls[t4 * 4 + 2][cl] = v.z * sw + sb;
        Ls[t4 * 4 + 3][cl] = v.w * sw + sb;
    }
    __syncthreads();
    {
        int row = tid >> 2, cq = (tid & 3) * 16;
        unsigned tmp[8];
        #pragma unroll
        for (int i = 0; i < 8; ++i)
            tmp[i] = pk2bf(Ls[row][cq + 2 * i], Ls[row][cq + 2 * i + 1]);
        uint4* dst = (uint4*)&normT[((size_t)b * kT + t0 + row) * kC + c0 + cq];
        dst[0] = make_uint4(tmp[0], tmp[1], tmp[2], tmp[3]);
        dst[1] = make_uint4(tmp[4], tmp[5], tmp[6], tmp[7]);
    }
}

// ---------------------------------------------------------------------------
// Kernel 3: qkv GEMM (bf16 MFMA). R20: t-tile 128 -> 256 (grid 1536 -> 768
// blocks): halves A-restaging traffic and barrier count per output element.
// Per wave: m-half 32 x t-half 128 (acc[2][8]). LDS: As 9KB + Bs 36KB.
// Epilogue writes q/k/v in PRE-FRAGMENTED MFMA operand layouts:
//   q/k: frag[tb=t/32][ks=c/16][hi=(c/8)&1][ln=t&31][e=c&7]
//   v:   frag[sg=s/16][hi=(s/8)&1][c][e=s&7]
// ---------------------------------------------------------------------------
__global__ __launch_bounds__(256) void qkv_gemm_kernel(const unsigned short* __restrict__ wbf,
                                                       const float* __restrict__ qkv_b,
                                                       const unsigned short* __restrict__ normT,
                                                       unsigned short* __restrict__ qTg,
                                                       unsigned short* __restrict__ kTg,
                                                       unsigned short* __restrict__ vCg) {
    constexpr int LDK = 72;
    constexpr int LDV = 264;   // v-staging row length (bf16), 528 B, 16B-aligned
    __shared__ __align__(16) unsigned short As[64 * LDK];
    __shared__ __align__(16) unsigned short Bs[256 * LDK];   // also epilogue staging

    int t0 = blockIdx.x * 256;
    int m0 = blockIdx.y * 64;
    int b  = blockIdx.z;
    const unsigned short* Ab = wbf + (size_t)m0 * kC;
    const unsigned short* Bb = normT + (size_t)b * kT * kC;

    int tid = threadIdx.x;
    int wave = tid >> 6, lane = tid & 63;
    int ln15 = lane & 15, quad = lane >> 4;
    int wm = wave >> 1, wt = wave & 1;

    f32x4 acc[2][8] = {};

    for (int k0 = 0; k0 < kC; k0 += 64) {
        __syncthreads();
        #pragma unroll
        for (int p = 0; p < 2; ++p) {
            int idx = tid + p * 256;
            int row = idx >> 3, seg = idx & 7;
            *(uint4*)&As[row * LDK + seg * 8] =
                *(const uint4*)&Ab[(size_t)row * kC + k0 + seg * 8];
        }
        #pragma unroll
        for (int p = 0; p < 8; ++p) {
            int idx = tid + p * 256;
            int row = idx >> 3, seg = idx & 7;
            *(uint4*)&Bs[row * LDK + seg * 8] =
                *(const uint4*)&Bb[(size_t)(t0 + row) * kC + k0 + seg * 8];
        }
        __syncthreads();
        #pragma unroll
        for (int ks = 0; ks < 2; ++ks) {
            bf16x8 af[2], bf[8];
            #pragma unroll
            for (int i = 0; i < 2; ++i)
                af[i] = *(bf16x8*)&As[(wm * 32 + i * 16 + ln15) * LDK + ks * 32 + quad * 8];
            #pragma unroll
            for (int j = 0; j < 8; ++j)
                bf[j] = *(bf16x8*)&Bs[(wt * 128 + j * 16 + ln15) * LDK + ks * 32 + quad * 8];
            #pragma unroll
            for (int i = 0; i < 2; ++i)
                #pragma unroll
                for (int j = 0; j < 8; ++j)
                    acc[i][j] = __builtin_amdgcn_mfma_f32_16x16x32_bf16(
                        af[i], bf[j], acc[i][j], 0, 0, 0);
        }
    }

    int type = (m0 % 192) / 64;   // 0=q, 1=k, 2=v
    int h = m0 / 192;
    int bh = b * kH + h;
    __syncthreads();   // all MFMA reads of Bs done; reuse Bs as staging
    #pragma unroll
    for (int i = 0; i < 2; ++i) {
        float4 bv = *(const float4*)&qkv_b[m0 + wm * 32 + i * 16 + quad * 4];
        const float* bp = (const float*)&bv;
        #pragma unroll
        for (int j = 0; j < 8; ++j) {
            int tl = wt * 128 + j * 16 + ln15;
            int c = wm * 32 + i * 16 + quad * 4;
            float v0 = acc[i][j][0] + bp[0];
            float v1 = acc[i][j][1] + bp[1];
            float v2 = acc[i][j][2] + bp[2];
            float v3 = acc[i][j][3] + bp[3];
            if (type == 0) {
                v0 *= kQScale; v1 *= kQScale; v2 *= kQScale; v3 *= kQScale;
            }
            if (type != 2) {
                *(uint2*)&Bs[tl * LDK + c] = make_uint2(pk2bf(v0, v1), pk2bf(v2, v3));
            } else {
                Bs[(c + 0) * LDV + tl] = f2bf(v0);
                Bs[(c + 1) * LDV + tl] = f2bf(v1);
                Bs[(c + 2) * LDV + tl] = f2bf(v2);
                Bs[(c + 3) * LDV + tl] = f2bf(v3);
            }
        }
    }
    __syncthreads();
    if (type != 2) {
        unsigned short* base = ((type == 0) ? qTg : kTg) + (size_t)bh * (kT * kCh);
        #pragma unroll
        for (int p = 0; p < 8; ++p) {
            int f = tid + p * 256;
            int ln = f & 31, hif = (f >> 5) & 1, ks = (f >> 6) & 3, tb = f >> 8;
            *(uint4*)&base[((t0 >> 5) + tb) * 2048 + ks * 512 + hif * 256 + ln * 8] =
                *(uint4*)&Bs[(tb * 32 + ln) * LDK + ks * 16 + hif * 8];
        }
    } else {
        unsigned short* base = vCg + (size_t)bh * (kT * kCh);
        #pragma unroll
        for (int p = 0; p < 8; ++p) {
            int f = tid + p * 256;
            int c = f & 63, hif = (f >> 6) & 1, sg = f >> 7;
            *(uint4*)&base[((t0 >> 4) + sg) * 1024 + hif * 512 + c * 8] =
                *(uint4*)&Bs[c * LDV + sg * 16 + hif * 8];
        }
    }
}

// ---------------------------------------------------------------------------
// Kernel 4: REGISTER-ONLY MFMA flash attention (R16 config — best measured,
// 77.0us). R19 falsified the register-cap theory (1 wave/SIMD + 512 regs =
// 83us, WORSE); attn is bracketed 77-95us across 6 structural variants and
// is parked here. Each wave owns 64 t (two 32-t chunks A,B); wave = (tc,
// s-half); XCD-chunked swizzle; ping-pong K/V prefetch with sched_barrier
// pins; partials combined once via LDS.
// C-layout: col t=lane&31, row s=(reg&3)+8*(reg>>2)+4*hi (m74/m101).
// ---------------------------------------------------------------------------
__global__ __launch_bounds__(256, 2) void attn_mfma_kernel(const unsigned short* __restrict__ qTg,
                                                           const unsigned short* __restrict__ kTg,
                                                           const unsigned short* __restrict__ vCg,
                                                           unsigned short* __restrict__ attnT) {
    __shared__ float Ored[2][2][32][64];   // [tc][chunk][acc elem][lane]
    __shared__ float Lred[2][2][64];

    // XCD-chunked work remap: 512 blocks / 8 XCDs -> 64 consecutive work
    // items (= 2 full bh) per XCD. Bijective since 512 % 8 == 0.
    int lid = blockIdx.y * 32 + blockIdx.x;
    int wl  = (lid & 7) * 64 + (lid >> 3);
    int bh  = wl >> 5;
    int t0  = (wl & 31) * 128;
    int b = bh >> 2, h = bh & 3;

    int tid = threadIdx.x;
    int wave = tid >> 6, lane = tid & 63;
    int ln31 = lane & 31, hi = lane >> 5;
    int tc = wave & 1;    // which 64-t span of the block's 128 t
    int sh = wave >> 1;   // which 2048-s half of the KV range

    const unsigned short* qb = qTg + (size_t)bh * (kT * kCh);
    const unsigned short* kb = kTg + (size_t)bh * (kT * kCh);
    const unsigned short* vb = vCg + (size_t)bh * (kT * kCh);

    // Q fragments for the wave's two 32-t chunks (loop-invariant)
    bf16x8 qA[4], qB[4];
    {
        const unsigned short* qp = qb + ((size_t)(t0 >> 5) + tc * 2) * 2048 + hi * 256 + ln31 * 8;
        #pragma unroll
        for (int ks = 0; ks < 4; ++ks) {
            qA[ks] = *(const bf16x8*)(qp + ks * 512);
            qB[ks] = *(const bf16x8*)(qp + 2048 + ks * 512);
        }
    }

    // K tile idx: 2048 shorts per 32-s tile. V: same stride (2 x 16-s groups).
    const unsigned short* kbase = kb + (size_t)sh * 131072 + hi * 256 + ln31 * 8;
    const unsigned short* vbase = vb + (size_t)sh * 131072 + hi * 512 + ln31 * 8;

    float lA = 0.f, lB = 0.f;
    f32x16 oA0 = {}, oA1 = {}, oB0 = {}, oB1 = {};

    auto loadKV = [&](bf16x8* kf, bf16x8* vf, int idx) {
        const unsigned short* kp = kbase + (size_t)idx * 2048;
        const unsigned short* vp = vbase + (size_t)idx * 2048;
        kf[0] = *(const bf16x8*)(kp);
        kf[1] = *(const bf16x8*)(kp + 512);
        kf[2] = *(const bf16x8*)(kp + 1024);
        kf[3] = *(const bf16x8*)(kp + 1536);
        vf[0] = *(const bf16x8*)(vp);           // ct=0, s-chunk 0
        vf[1] = *(const bf16x8*)(vp + 256);     // ct=1, s-chunk 0
        vf[2] = *(const bf16x8*)(vp + 1024);    // ct=0, s-chunk 1
        vf[3] = *(const bf16x8*)(vp + 1280);    // ct=1, s-chunk 1
    };

    auto softmax_pack = [&](const f32x16& s, float& l, bf16x8& f0, bf16x8& f1) {
        unsigned u00, u01, u10, u11, u20, u21, u30, u31;
        {
            float p0 = __builtin_amdgcn_exp2f(s[0]);
            float p1 = __builtin_amdgcn_exp2f(s[1]);
            float p2 = __builtin_amdgcn_exp2f(s[2]);
            float p3 = __builtin_amdgcn_exp2f(s[3]);
            l += (p0 + p1) + (p2 + p3);
            u00 = pk2bf_trunc(p0, p1); u01 = pk2bf_trunc(p2, p3);
        }
        {
            float p0 = __builtin_amdgcn_exp2f(s[4]);
            float p1 = __builtin_amdgcn_exp2f(s[5]);
            float p2 = __builtin_amdgcn_exp2f(s[6]);
            float p3 = __builtin_amdgcn_exp2f(s[7]);
            l += (p0 + p1) + (p2 + p3);
            u10 = pk2bf_trunc(p0, p1); u11 = pk2bf_trunc(p2, p3);
        }
        {
            float p0 = __builtin_amdgcn_exp2f(s[8]);
            float p1 = __builtin_amdgcn_exp2f(s[9]);
            float p2 = __builtin_amdgcn_exp2f(s[10]);
            float p3 = __builtin_amdgcn_exp2f(s[11]);
            l += (p0 + p1) + (p2 + p3);
            u20 = pk2bf_trunc(p0, p1); u21 = pk2bf_trunc(p2, p3);
        }
        {
            float p0 = __builtin_amdgcn_exp2f(s[12]);
            float p1 = __builtin_amdgcn_exp2f(s[13]);
            float p2 = __builtin_amdgcn_exp2f(s[14]);
            float p3 = __builtin_amdgcn_exp2f(s[15]);
            l += (p0 + p1) + (p2 + p3);
            u30 = pk2bf_trunc(p0, p1); u31 = pk2bf_trunc(p2, p3);
        }
        // C-layout -> B-operand, in-register (T12): u[g][w] holds
        // s=(8g+4h+2w,+1); swap(u[g],u[g+1]) yields fragment words for
        // s-chunks [16i+8h, 16i+8h+8).
        pls32(u00, u10); pls32(u01, u11);
        pls32(u20, u30); pls32(u21, u31);
        PunP P0, P1;
        P0.u = make_uint4(u00, u01, u10, u11);
        P1.u = make_uint4(u20, u21, u30, u31);
        f0 = P0.f; f1 = P1.f;
    };

    auto computeTile = [&](const bf16x8* kf, const bf16x8* vf) {
        f32x16 sA = {}, sB = {};
        __builtin_amdgcn_s_setprio(1);
        #pragma unroll
        for (int ks = 0; ks < 4; ++ks) {
            sA = __builtin_amdgcn_mfma_f32_32x32x16_bf16(kf[ks], qA[ks], sA, 0, 0, 0);
            sB = __builtin_amdgcn_mfma_f32_32x32x16_bf16(kf[ks], qB[ks], sB, 0, 0, 0);
        }
        __builtin_amdgcn_s_setprio(0);
        bf16x8 FA0, FA1, FB0, FB1;
        softmax_pack(sA, lA, FA0, FA1);
        softmax_pack(sB, lB, FB0, FB1);
        __builtin_amdgcn_s_setprio(1);
        oA0 = __builtin_amdgcn_mfma_f32_32x32x16_bf16(vf[0], FA0, oA0, 0, 0, 0);
        oA1 = __builtin_amdgcn_mfma_f32_32x32x16_bf16(vf[1], FA0, oA1, 0, 0, 0);
        oB0 = __builtin_amdgcn_mfma_f32_32x32x16_bf16(vf[0], FB0, oB0, 0, 0, 0);
        oB1 = __builtin_amdgcn_mfma_f32_32x32x16_bf16(vf[1], FB0, oB1, 0, 0, 0);
        oA0 = __builtin_amdgcn_mfma_f32_32x32x16_bf16(vf[2], FA1, oA0, 0, 0, 0);
        oA1 = __builtin_amdgcn_mfma_f32_32x32x16_bf16(vf[3], FA1, oA1, 0, 0, 0);
        oB0 = __builtin_amdgcn_mfma_f32_32x32x16_bf16(vf[2], FB1, oB0, 0, 0, 0);
        oB1 = __builtin_amdgcn_mfma_f32_32x32x16_bf16(vf[3], FB1, oB1, 0, 0, 0);
        __builtin_amdgcn_s_setprio(0);
    };

    bf16x8 kX[4], vX[4], kY[4], vY[4];
    loadKV(kX, vX, 0);
    __builtin_amdgcn_sched_barrier(0);
    #pragma unroll 1
    for (int it = 0; it < 64; it += 2) {
        loadKV(kY, vY, it + 1);              // prefetch next tile
        __builtin_amdgcn_sched_barrier(0);   // PIN: loads may not sink below
        computeTile(kX, vX);
        loadKV(kX, vX, (it + 2) & 63);       // wrap-load on last trip (unused)
        __builtin_amdgcn_sched_barrier(0);   // PIN
        computeTile(kY, vY);
    }

    // ---- combine the two lane-halves' s-subsets
    lA += __shfl_xor(lA, 32);
    lB += __shfl_xor(lB, 32);

    // ---- cross-wave combine of the two s-halves (one-time LDS reduction)
    if (sh == 1) {
        #pragma unroll
        for (int e = 0; e < 16; ++e) {
            Ored[tc][0][e][lane]      = oA0[e];
            Ored[tc][0][16 + e][lane] = oA1[e];
            Ored[tc][1][e][lane]      = oB0[e];
            Ored[tc][1][16 + e][lane] = oB1[e];
        }
        Lred[tc][0][lane] = lA;
        Lred[tc][1][lane] = lB;
    }
    __syncthreads();
    if (sh == 0) {
        #pragma unroll
        for (int e = 0; e < 16; ++e) {
            oA0[e] += Ored[tc][0][e][lane];
            oA1[e] += Ored[tc][0][16 + e][lane];
            oB0[e] += Ored[tc][1][e][lane];
            oB1[e] += Ored[tc][1][16 + e][lane];
        }
        lA += Lred[tc][0][lane];
        lB += Lred[tc][1][lane];
        #pragma unroll
        for (int ch = 0; ch < 2; ++ch) {
            float linv = 1.0f / (ch ? lB : lA);
            int t = t0 + tc * 64 + ch * 32 + ln31;
            #pragma unroll
            for (int ct = 0; ct < 2; ++ct) {
                const f32x16& ao = ch ? (ct ? oB1 : oB0) : (ct ? oA1 : oA0);
                #pragma unroll
                for (int g = 0; g < 4; ++g) {
                    int c = h * kCh + ct * 32 + 8 * g + 4 * hi;
                    float v0 = ao[4 * g + 0] * linv;
                    float v1 = ao[4 * g + 1] * linv;
                    float v2 = ao[4 * g + 2] * linv;
                    float v3 = ao[4 * g + 3] * linv;
                    *(uint2*)&attnT[((size_t)b * kT + t) * kC + c] =
                        make_uint2(pk2bf(v0, v1), pk2bf(v2, v3));
                }
            }
        }
    }
}

// ---------------------------------------------------------------------------
// Kernel 5: proj GEMM + bias + residual -> fp32. R20: t-tile 128 -> 256
// (grid 512 -> 256 blocks), same mechanics as qkv.
// ---------------------------------------------------------------------------
__global__ __launch_bounds__(256) void proj_gemm_kernel(const unsigned short* __restrict__ wpbf,
                                                        const float* __restrict__ proj_b,
                                                        const unsigned short* __restrict__ attnT,
                                                        const float* __restrict__ x,
                                                        float* __restrict__ out) {
    constexpr int LDK = 72;
    __shared__ __align__(16) unsigned short As[64 * LDK];
    __shared__ __align__(16) unsigned short Bs[256 * LDK];

    int t0 = blockIdx.x * 256;
    int m0 = blockIdx.y * 64;
    int b  = blockIdx.z;
    const unsigned short* Ab = wpbf + (size_t)m0 * kC;
    const unsigned short* Bb = attnT + (size_t)b * kT * kC;

    int tid = threadIdx.x;
    int wave = tid >> 6, lane = tid & 63;
    int ln15 = lane & 15, quad = lane >> 4;
    int wm = wave >> 1, wt = wave & 1;

    f32x4 acc[2][8] = {};

    for (int k0 = 0; k0 < kC; k0 += 64) {
        __syncthreads();
        #pragma unroll
        for (int p = 0; p < 2; ++p) {
            int idx = tid + p * 256;
            int row = idx >> 3, seg = idx & 7;
            *(uint4*)&As[row * LDK + seg * 8] =
                *(const uint4*)&Ab[(size_t)row * kC + k0 + seg * 8];
        }
        #pragma unroll
        for (int p = 0; p < 8; ++p) {
            int idx = tid + p * 256;
            int row = idx >> 3, seg = idx & 7;
            *(uint4*)&Bs[row * LDK + seg * 8] =
                *(const uint4*)&Bb[(size_t)(t0 + row) * kC + k0 + seg * 8];
        }
        __syncthreads();
        #pragma unroll
        for (int ks = 0; ks < 2; ++ks) {
            bf16x8 af[2], bf[8];
            #pragma unroll
            for (int i = 0; i < 2; ++i)
                af[i] = *(bf16x8*)&As[(wm * 32 + i * 16 + ln15) * LDK + ks * 32 + quad * 8];
            #pragma unroll
            for (int j = 0; j < 8; ++j)
                bf[j] = *(bf16x8*)&Bs[(wt * 128 + j * 16 + ln15) * LDK + ks * 32 + quad * 8];
            #pragma unroll
            for (int i = 0; i < 2; ++i)
                #pragma unroll
                for (int j = 0; j < 8; ++j)
                    acc[i][j] = __builtin_amdgcn_mfma_f32_16x16x32_bf16(
                        af[i], bf[j], acc[i][j], 0, 0, 0);
        }
    }

    #pragma unroll
    for (int i = 0; i < 2; ++i) {
        float4 bv = *(const float4*)&proj_b[m0 + wm * 32 + i * 16 + quad * 4];
        const float* bp = (const float*)&bv;
        #pragma unroll
        for (int j = 0; j < 8; ++j) {
            int t = t0 + wt * 128 + j * 16 + ln15;
            int mbase = m0 + wm * 32 + i * 16 + quad * 4;
            #pragma unroll
            for (int r = 0; r < 4; ++r) {
                size_t off = ((size_t)b * kC + mbase + r) * kT + t;
                out[off] = acc[i][j][r] + bp[r] + x[off];
            }
        }
    }
}

// ---------------------------------------------------------------------------
extern "C" void kernel_launch(void* const* d_in, const int* in_sizes, int n_in,
                              void* d_out, int out_size, void* d_ws, size_t ws_size,
                              hipStream_t stream) {
    const float* x      = (const float*)d_in[0];
    const float* norm_w = (const float*)d_in[1];
    const float* norm_b = (const float*)d_in[2];
    const float* qkv_w  = (const float*)d_in[3];
    const float* qkv_b  = (const float*)d_in[4];
    const float* proj_w = (const float*)d_in[5];
    const float* proj_b = (const float*)d_in[6];
    float* out = (float*)d_out;

    // Workspace: stats fp32[128] | bf16: normT[4.19M] wbf[262144] qT kT vC attnT[4.19M each]
    float* stats = (float*)d_ws;
    unsigned short* wsbf  = (unsigned short*)((float*)d_ws + 128);
    unsigned short* normT = wsbf;
    unsigned short* wbf   = normT + (size_t)kB * kT * kC;
    unsigned short* qTp   = wbf + 262144;
    unsigned short* kTp   = qTp + (size_t)kB * kH * kT * kCh;
    unsigned short* vCp   = kTp + (size_t)kB * kH * kT * kCh;
    unsigned short* attnT = vCp + (size_t)kB * kH * kT * kCh;
    unsigned short* wpbf  = wbf + 196608;

    hipMemsetAsync(d_ws, 0, 128 * sizeof(float), stream);   // zero stats sums
    prep_kernel<<<384, 256, 0, stream>>>(x, stats, qkv_w, proj_w, wbf);
    gn_apply_t_kernel<<<dim3(kT / 64, kC / 64, kB), 256, 0, stream>>>(
        x, stats, norm_w, norm_b, normT);
    qkv_gemm_kernel<<<dim3(kT / 256, 12, kB), 256, 0, stream>>>(
        wbf, qkv_b, normT, qTp, kTp, vCp);
    attn_mfma_kernel<<<dim3(kT / 128, kB * kH), 256, 0, stream>>>(qTp, kTp, vCp, attnT);
    proj_gemm_kernel<<<dim3(kT / 256, kC / 64, kB), 256, 0, stream>>>(
        wpbf, proj_b, attnT, x, out);
}

// Round 9
// 183.959 us; speedup vs baseline: 1.0875x; 1.0054x over previous
//
#include <hip/hip_runtime.h>

// Problem constants (B=4, C=256, H=W=64 -> T=4096)
constexpr int kB  = 4;
constexpr int kC  = 256;
constexpr int kT  = 4096;
constexpr int kG  = 16;
constexpr int kCg = kC / kG;   // 16 channels per group
constexpr int kH  = 4;         // heads
constexpr int kCh = kC / kH;   // 64 channels per head
constexpr float kEps = 1e-5f;
// q scale: 1/8 (=scale^2) folded with log2(e) for exp2-domain softmax
constexpr float kQScale = 0.125f * 1.4426950408889634f;

typedef short bf16x8 __attribute__((ext_vector_type(8)));
typedef float f32x4  __attribute__((ext_vector_type(4)));
typedef float f32x16 __attribute__((ext_vector_type(16)));

union PunP { uint4 u; bf16x8 f; };

__device__ inline unsigned short f2bf(float f) {
    union { float f; unsigned u; } v; v.f = f;
    unsigned r = v.u + 0x7fffu + ((v.u >> 16) & 1u);   // RNE
    return (unsigned short)(r >> 16);
}
__device__ inline unsigned pk2bf(float a, float b) {
    return (unsigned)f2bf(a) | ((unsigned)f2bf(b) << 16);
}
// truncating pack of two fp32 -> bf16x2 in ONE v_perm_b32 (high halves)
__device__ inline unsigned pk2bf_trunc(float a, float b) {
    return __builtin_amdgcn_perm(__float_as_uint(b), __float_as_uint(a), 0x07060302u);
}
// v_permlane32_swap_b32: a[32:63] <-> b[0:31].
__device__ inline void pls32(unsigned& a, unsigned& b) {
    __asm__("v_permlane32_swap_b32 %0, %1" : "+v"(a), "+v"(b));
}

// ---------------------------------------------------------------------------
// Kernel 1: GroupNorm statistics + weight fp32->bf16 convert.
// R21: partial sums go to DISJOINT slots stats[(bg*4+part)*2] (plain
// stores, no atomics) -> no zeroing needed -> the hipMemsetAsync dispatch
// is eliminated. This is the single-variable test of the ~10us/dispatch
// overhead hypothesis (R20 accounting: ~60us of the non-attn 104us is
// unexplained by kernel rooflines; 6 dispatches).
// ---------------------------------------------------------------------------
__global__ __launch_bounds__(256) void prep_kernel(const float* __restrict__ x,
                                                   float* __restrict__ stats,
                                                   const float* __restrict__ qkv_w,
                                                   const float* __restrict__ proj_w,
                                                   unsigned short* __restrict__ wbf) {
    int tid = threadIdx.x;
    if (blockIdx.x >= 256) {
        int gid = (blockIdx.x - 256) * 256 + tid;
        for (int i = gid; i < 65536; i += 128 * 256) {
            float4 v = (i < 49152) ? ((const float4*)qkv_w)[i]
                                   : ((const float4*)proj_w)[i - 49152];
            *(uint2*)&wbf[(size_t)i * 4] = make_uint2(pk2bf(v.x, v.y), pk2bf(v.z, v.w));
        }
        return;
    }
    int bg = blockIdx.x >> 2, part = blockIdx.x & 3;
    // Each block reads 1/4 of one group's 65536 floats: 4096 float4s.
    const float4* xp4 = (const float4*)(x + (size_t)bg * (kCg * kT)) + part * 4096;
    float s = 0.f, q = 0.f;
    #pragma unroll 4
    for (int i = 0; i < 16; ++i) {
        float4 v = xp4[tid + i * 256];
        s += v.x + v.y + v.z + v.w;
        q += v.x * v.x + v.y * v.y + v.z * v.z + v.w * v.w;
    }
    #pragma unroll
    for (int off = 32; off > 0; off >>= 1) {
        s += __shfl_down(s, off);
        q += __shfl_down(q, off);
    }
    __shared__ float rs[4], rq[4];
    int wid = tid >> 6, lane = tid & 63;
    if (lane == 0) { rs[wid] = s; rq[wid] = q; }
    __syncthreads();
    if (tid == 0) {
        float S = rs[0] + rs[1] + rs[2] + rs[3];
        float Q = rq[0] + rq[1] + rq[2] + rq[3];
        stats[blockIdx.x * 2 + 0] = S;   // slot (bg*4+part): every slot
        stats[blockIdx.x * 2 + 1] = Q;   // written each launch, no races
    }
}

// ---------------------------------------------------------------------------
// Kernel 2: apply GroupNorm affine + transpose -> normT[b][t][c] bf16.
// stats[] holds 4 raw (sum, sumsq) partials per group; summed here.
// ---------------------------------------------------------------------------
__global__ __launch_bounds__(256) void gn_apply_t_kernel(const float* __restrict__ x,
                                                         const float* __restrict__ stats,
                                                         const float* __restrict__ w,
                                                         const float* __restrict__ bias,
                                                         unsigned short* __restrict__ normT) {
    __shared__ float Ls[64][65];
    int t0 = blockIdx.x * 64;
    int c0 = blockIdx.y * 64;
    int b  = blockIdx.z;
    int tid = threadIdx.x;
    const float invN = 1.0f / (float)(kCg * kT);
    #pragma unroll
    for (int p = 0; p < 4; ++p) {
        int idx = tid + p * 256;
        int cl = idx >> 4, t4 = idx & 15;
        int c = c0 + cl;
        int bg = b * kG + (c >> 4);
        float S = 0.f, Q = 0.f;
        #pragma unroll
        for (int pr = 0; pr < 4; ++pr) {
            S += stats[(bg * 4 + pr) * 2 + 0];
            Q += stats[(bg * 4 + pr) * 2 + 1];
        }
        float mean = S * invN;
        float rstd = rsqrtf(Q * invN - mean * mean + kEps);
        float sw = w[c] * rstd;
        float sb = bias[c] - mean * sw;
        float4 v = *(const float4*)&x[((size_t)b * kC + c) * kT + t0 + t4 * 4];
        Ls[t4 * 4 + 0][cl] = v.x * sw + sb;
        Ls[t4 * 4 + 1][cl] = v.y * sw + sb;
        Ls[t4 * 4 + 2][cl] = v.z * sw + sb;
        Ls[t4 * 4 + 3][cl] = v.w * sw + sb;
    }
    __syncthreads();
    {
        int row = tid >> 2, cq = (tid & 3) * 16;
        unsigned tmp[8];
        #pragma unroll
        for (int i = 0; i < 8; ++i)
            tmp[i] = pk2bf(Ls[row][cq + 2 * i], Ls[row][cq + 2 * i + 1]);
        uint4* dst = (uint4*)&normT[((size_t)b * kT + t0 + row) * kC + c0 + cq];
        dst[0] = make_uint4(tmp[0], tmp[1], tmp[2], tmp[3]);
        dst[1] = make_uint4(tmp[4], tmp[5], tmp[6], tmp[7]);
    }
}

// ---------------------------------------------------------------------------
// Kernel 3: qkv GEMM (bf16 MFMA), R20 structure (t-tile 256, 768 blocks).
// Epilogue writes q/k/v in PRE-FRAGMENTED MFMA operand layouts:
//   q/k: frag[tb=t/32][ks=c/16][hi=(c/8)&1][ln=t&31][e=c&7]
//   v:   frag[sg=s/16][hi=(s/8)&1][c][e=s&7]
// ---------------------------------------------------------------------------
__global__ __launch_bounds__(256) void qkv_gemm_kernel(const unsigned short* __restrict__ wbf,
                                                       const float* __restrict__ qkv_b,
                                                       const unsigned short* __restrict__ normT,
                                                       unsigned short* __restrict__ qTg,
                                                       unsigned short* __restrict__ kTg,
                                                       unsigned short* __restrict__ vCg) {
    constexpr int LDK = 72;
    constexpr int LDV = 264;   // v-staging row length (bf16), 528 B, 16B-aligned
    __shared__ __align__(16) unsigned short As[64 * LDK];
    __shared__ __align__(16) unsigned short Bs[256 * LDK];   // also epilogue staging

    int t0 = blockIdx.x * 256;
    int m0 = blockIdx.y * 64;
    int b  = blockIdx.z;
    const unsigned short* Ab = wbf + (size_t)m0 * kC;
    const unsigned short* Bb = normT + (size_t)b * kT * kC;

    int tid = threadIdx.x;
    int wave = tid >> 6, lane = tid & 63;
    int ln15 = lane & 15, quad = lane >> 4;
    int wm = wave >> 1, wt = wave & 1;

    f32x4 acc[2][8] = {};

    for (int k0 = 0; k0 < kC; k0 += 64) {
        __syncthreads();
        #pragma unroll
        for (int p = 0; p < 2; ++p) {
            int idx = tid + p * 256;
            int row = idx >> 3, seg = idx & 7;
            *(uint4*)&As[row * LDK + seg * 8] =
                *(const uint4*)&Ab[(size_t)row * kC + k0 + seg * 8];
        }
        #pragma unroll
        for (int p = 0; p < 8; ++p) {
            int idx = tid + p * 256;
            int row = idx >> 3, seg = idx & 7;
            *(uint4*)&Bs[row * LDK + seg * 8] =
                *(const uint4*)&Bb[(size_t)(t0 + row) * kC + k0 + seg * 8];
        }
        __syncthreads();
        #pragma unroll
        for (int ks = 0; ks < 2; ++ks) {
            bf16x8 af[2], bf[8];
            #pragma unroll
            for (int i = 0; i < 2; ++i)
                af[i] = *(bf16x8*)&As[(wm * 32 + i * 16 + ln15) * LDK + ks * 32 + quad * 8];
            #pragma unroll
            for (int j = 0; j < 8; ++j)
                bf[j] = *(bf16x8*)&Bs[(wt * 128 + j * 16 + ln15) * LDK + ks * 32 + quad * 8];
            #pragma unroll
            for (int i = 0; i < 2; ++i)
                #pragma unroll
                for (int j = 0; j < 8; ++j)
                    acc[i][j] = __builtin_amdgcn_mfma_f32_16x16x32_bf16(
                        af[i], bf[j], acc[i][j], 0, 0, 0);
        }
    }

    int type = (m0 % 192) / 64;   // 0=q, 1=k, 2=v
    int h = m0 / 192;
    int bh = b * kH + h;
    __syncthreads();   // all MFMA reads of Bs done; reuse Bs as staging
    #pragma unroll
    for (int i = 0; i < 2; ++i) {
        float4 bv = *(const float4*)&qkv_b[m0 + wm * 32 + i * 16 + quad * 4];
        const float* bp = (const float*)&bv;
        #pragma unroll
        for (int j = 0; j < 8; ++j) {
            int tl = wt * 128 + j * 16 + ln15;
            int c = wm * 32 + i * 16 + quad * 4;
            float v0 = acc[i][j][0] + bp[0];
            float v1 = acc[i][j][1] + bp[1];
            float v2 = acc[i][j][2] + bp[2];
            float v3 = acc[i][j][3] + bp[3];
            if (type == 0) {
                v0 *= kQScale; v1 *= kQScale; v2 *= kQScale; v3 *= kQScale;
            }
            if (type != 2) {
                *(uint2*)&Bs[tl * LDK + c] = make_uint2(pk2bf(v0, v1), pk2bf(v2, v3));
            } else {
                Bs[(c + 0) * LDV + tl] = f2bf(v0);
                Bs[(c + 1) * LDV + tl] = f2bf(v1);
                Bs[(c + 2) * LDV + tl] = f2bf(v2);
                Bs[(c + 3) * LDV + tl] = f2bf(v3);
            }
        }
    }
    __syncthreads();
    if (type != 2) {
        unsigned short* base = ((type == 0) ? qTg : kTg) + (size_t)bh * (kT * kCh);
        #pragma unroll
        for (int p = 0; p < 8; ++p) {
            int f = tid + p * 256;
            int ln = f & 31, hif = (f >> 5) & 1, ks = (f >> 6) & 3, tb = f >> 8;
            *(uint4*)&base[((t0 >> 5) + tb) * 2048 + ks * 512 + hif * 256 + ln * 8] =
                *(uint4*)&Bs[(tb * 32 + ln) * LDK + ks * 16 + hif * 8];
        }
    } else {
        unsigned short* base = vCg + (size_t)bh * (kT * kCh);
        #pragma unroll
        for (int p = 0; p < 8; ++p) {
            int f = tid + p * 256;
            int c = f & 63, hif = (f >> 6) & 1, sg = f >> 7;
            *(uint4*)&base[((t0 >> 4) + sg) * 1024 + hif * 512 + c * 8] =
                *(uint4*)&Bs[c * LDV + sg * 16 + hif * 8];
        }
    }
}

// ---------------------------------------------------------------------------
// Kernel 4: REGISTER-ONLY MFMA flash attention (R16 config — best measured).
// attn is bracketed 77-95us across 6 structural variants and parked.
// Each wave owns 64 t (two 32-t chunks A,B); wave = (tc, s-half);
// XCD-chunked swizzle; ping-pong K/V prefetch with sched_barrier pins;
// partials combined once via LDS.
// C-layout: col t=lane&31, row s=(reg&3)+8*(reg>>2)+4*hi (m74/m101).
// ---------------------------------------------------------------------------
__global__ __launch_bounds__(256, 2) void attn_mfma_kernel(const unsigned short* __restrict__ qTg,
                                                           const unsigned short* __restrict__ kTg,
                                                           const unsigned short* __restrict__ vCg,
                                                           unsigned short* __restrict__ attnT) {
    __shared__ float Ored[2][2][32][64];   // [tc][chunk][acc elem][lane]
    __shared__ float Lred[2][2][64];

    // XCD-chunked work remap: 512 blocks / 8 XCDs -> 64 consecutive work
    // items (= 2 full bh) per XCD. Bijective since 512 % 8 == 0.
    int lid = blockIdx.y * 32 + blockIdx.x;
    int wl  = (lid & 7) * 64 + (lid >> 3);
    int bh  = wl >> 5;
    int t0  = (wl & 31) * 128;
    int b = bh >> 2, h = bh & 3;

    int tid = threadIdx.x;
    int wave = tid >> 6, lane = tid & 63;
    int ln31 = lane & 31, hi = lane >> 5;
    int tc = wave & 1;    // which 64-t span of the block's 128 t
    int sh = wave >> 1;   // which 2048-s half of the KV range

    const unsigned short* qb = qTg + (size_t)bh * (kT * kCh);
    const unsigned short* kb = kTg + (size_t)bh * (kT * kCh);
    const unsigned short* vb = vCg + (size_t)bh * (kT * kCh);

    // Q fragments for the wave's two 32-t chunks (loop-invariant)
    bf16x8 qA[4], qB[4];
    {
        const unsigned short* qp = qb + ((size_t)(t0 >> 5) + tc * 2) * 2048 + hi * 256 + ln31 * 8;
        #pragma unroll
        for (int ks = 0; ks < 4; ++ks) {
            qA[ks] = *(const bf16x8*)(qp + ks * 512);
            qB[ks] = *(const bf16x8*)(qp + 2048 + ks * 512);
        }
    }

    // K tile idx: 2048 shorts per 32-s tile. V: same stride (2 x 16-s groups).
    const unsigned short* kbase = kb + (size_t)sh * 131072 + hi * 256 + ln31 * 8;
    const unsigned short* vbase = vb + (size_t)sh * 131072 + hi * 512 + ln31 * 8;

    float lA = 0.f, lB = 0.f;
    f32x16 oA0 = {}, oA1 = {}, oB0 = {}, oB1 = {};

    auto loadKV = [&](bf16x8* kf, bf16x8* vf, int idx) {
        const unsigned short* kp = kbase + (size_t)idx * 2048;
        const unsigned short* vp = vbase + (size_t)idx * 2048;
        kf[0] = *(const bf16x8*)(kp);
        kf[1] = *(const bf16x8*)(kp + 512);
        kf[2] = *(const bf16x8*)(kp + 1024);
        kf[3] = *(const bf16x8*)(kp + 1536);
        vf[0] = *(const bf16x8*)(vp);           // ct=0, s-chunk 0
        vf[1] = *(const bf16x8*)(vp + 256);     // ct=1, s-chunk 0
        vf[2] = *(const bf16x8*)(vp + 1024);    // ct=0, s-chunk 1
        vf[3] = *(const bf16x8*)(vp + 1280);    // ct=1, s-chunk 1
    };

    auto softmax_pack = [&](const f32x16& s, float& l, bf16x8& f0, bf16x8& f1) {
        unsigned u00, u01, u10, u11, u20, u21, u30, u31;
        {
            float p0 = __builtin_amdgcn_exp2f(s[0]);
            float p1 = __builtin_amdgcn_exp2f(s[1]);
            float p2 = __builtin_amdgcn_exp2f(s[2]);
            float p3 = __builtin_amdgcn_exp2f(s[3]);
            l += (p0 + p1) + (p2 + p3);
            u00 = pk2bf_trunc(p0, p1); u01 = pk2bf_trunc(p2, p3);
        }
        {
            float p0 = __builtin_amdgcn_exp2f(s[4]);
            float p1 = __builtin_amdgcn_exp2f(s[5]);
            float p2 = __builtin_amdgcn_exp2f(s[6]);
            float p3 = __builtin_amdgcn_exp2f(s[7]);
            l += (p0 + p1) + (p2 + p3);
            u10 = pk2bf_trunc(p0, p1); u11 = pk2bf_trunc(p2, p3);
        }
        {
            float p0 = __builtin_amdgcn_exp2f(s[8]);
            float p1 = __builtin_amdgcn_exp2f(s[9]);
            float p2 = __builtin_amdgcn_exp2f(s[10]);
            float p3 = __builtin_amdgcn_exp2f(s[11]);
            l += (p0 + p1) + (p2 + p3);
            u20 = pk2bf_trunc(p0, p1); u21 = pk2bf_trunc(p2, p3);
        }
        {
            float p0 = __builtin_amdgcn_exp2f(s[12]);
            float p1 = __builtin_amdgcn_exp2f(s[13]);
            float p2 = __builtin_amdgcn_exp2f(s[14]);
            float p3 = __builtin_amdgcn_exp2f(s[15]);
            l += (p0 + p1) + (p2 + p3);
            u30 = pk2bf_trunc(p0, p1); u31 = pk2bf_trunc(p2, p3);
        }
        // C-layout -> B-operand, in-register (T12): u[g][w] holds
        // s=(8g+4h+2w,+1); swap(u[g],u[g+1]) yields fragment words for
        // s-chunks [16i+8h, 16i+8h+8).
        pls32(u00, u10); pls32(u01, u11);
        pls32(u20, u30); pls32(u21, u31);
        PunP P0, P1;
        P0.u = make_uint4(u00, u01, u10, u11);
        P1.u = make_uint4(u20, u21, u30, u31);
        f0 = P0.f; f1 = P1.f;
    };

    auto computeTile = [&](const bf16x8* kf, const bf16x8* vf) {
        f32x16 sA = {}, sB = {};
        __builtin_amdgcn_s_setprio(1);
        #pragma unroll
        for (int ks = 0; ks < 4; ++ks) {
            sA = __builtin_amdgcn_mfma_f32_32x32x16_bf16(kf[ks], qA[ks], sA, 0, 0, 0);
            sB = __builtin_amdgcn_mfma_f32_32x32x16_bf16(kf[ks], qB[ks], sB, 0, 0, 0);
        }
        __builtin_amdgcn_s_setprio(0);
        bf16x8 FA0, FA1, FB0, FB1;
        softmax_pack(sA, lA, FA0, FA1);
        softmax_pack(sB, lB, FB0, FB1);
        __builtin_amdgcn_s_setprio(1);
        oA0 = __builtin_amdgcn_mfma_f32_32x32x16_bf16(vf[0], FA0, oA0, 0, 0, 0);
        oA1 = __builtin_amdgcn_mfma_f32_32x32x16_bf16(vf[1], FA0, oA1, 0, 0, 0);
        oB0 = __builtin_amdgcn_mfma_f32_32x32x16_bf16(vf[0], FB0, oB0, 0, 0, 0);
        oB1 = __builtin_amdgcn_mfma_f32_32x32x16_bf16(vf[1], FB0, oB1, 0, 0, 0);
        oA0 = __builtin_amdgcn_mfma_f32_32x32x16_bf16(vf[2], FA1, oA0, 0, 0, 0);
        oA1 = __builtin_amdgcn_mfma_f32_32x32x16_bf16(vf[3], FA1, oA1, 0, 0, 0);
        oB0 = __builtin_amdgcn_mfma_f32_32x32x16_bf16(vf[2], FB1, oB0, 0, 0, 0);
        oB1 = __builtin_amdgcn_mfma_f32_32x32x16_bf16(vf[3], FB1, oB1, 0, 0, 0);
        __builtin_amdgcn_s_setprio(0);
    };

    bf16x8 kX[4], vX[4], kY[4], vY[4];
    loadKV(kX, vX, 0);
    __builtin_amdgcn_sched_barrier(0);
    #pragma unroll 1
    for (int it = 0; it < 64; it += 2) {
        loadKV(kY, vY, it + 1);              // prefetch next tile
        __builtin_amdgcn_sched_barrier(0);   // PIN: loads may not sink below
        computeTile(kX, vX);
        loadKV(kX, vX, (it + 2) & 63);       // wrap-load on last trip (unused)
        __builtin_amdgcn_sched_barrier(0);   // PIN
        computeTile(kY, vY);
    }

    // ---- combine the two lane-halves' s-subsets
    lA += __shfl_xor(lA, 32);
    lB += __shfl_xor(lB, 32);

    // ---- cross-wave combine of the two s-halves (one-time LDS reduction)
    if (sh == 1) {
        #pragma unroll
        for (int e = 0; e < 16; ++e) {
            Ored[tc][0][e][lane]      = oA0[e];
            Ored[tc][0][16 + e][lane] = oA1[e];
            Ored[tc][1][e][lane]      = oB0[e];
            Ored[tc][1][16 + e][lane] = oB1[e];
        }
        Lred[tc][0][lane] = lA;
        Lred[tc][1][lane] = lB;
    }
    __syncthreads();
    if (sh == 0) {
        #pragma unroll
        for (int e = 0; e < 16; ++e) {
            oA0[e] += Ored[tc][0][e][lane];
            oA1[e] += Ored[tc][0][16 + e][lane];
            oB0[e] += Ored[tc][1][e][lane];
            oB1[e] += Ored[tc][1][16 + e][lane];
        }
        lA += Lred[tc][0][lane];
        lB += Lred[tc][1][lane];
        #pragma unroll
        for (int ch = 0; ch < 2; ++ch) {
            float linv = 1.0f / (ch ? lB : lA);
            int t = t0 + tc * 64 + ch * 32 + ln31;
            #pragma unroll
            for (int ct = 0; ct < 2; ++ct) {
                const f32x16& ao = ch ? (ct ? oB1 : oB0) : (ct ? oA1 : oA0);
                #pragma unroll
                for (int g = 0; g < 4; ++g) {
                    int c = h * kCh + ct * 32 + 8 * g + 4 * hi;
                    float v0 = ao[4 * g + 0] * linv;
                    float v1 = ao[4 * g + 1] * linv;
                    float v2 = ao[4 * g + 2] * linv;
                    float v3 = ao[4 * g + 3] * linv;
                    *(uint2*)&attnT[((size_t)b * kT + t) * kC + c] =
                        make_uint2(pk2bf(v0, v1), pk2bf(v2, v3));
                }
            }
        }
    }
}

// ---------------------------------------------------------------------------
// Kernel 5: proj GEMM + bias + residual -> fp32 (R20 structure, t-tile 256).
// ---------------------------------------------------------------------------
__global__ __launch_bounds__(256) void proj_gemm_kernel(const unsigned short* __restrict__ wpbf,
                                                        const float* __restrict__ proj_b,
                                                        const unsigned short* __restrict__ attnT,
                                                        const float* __restrict__ x,
                                                        float* __restrict__ out) {
    constexpr int LDK = 72;
    __shared__ __align__(16) unsigned short As[64 * LDK];
    __shared__ __align__(16) unsigned short Bs[256 * LDK];

    int t0 = blockIdx.x * 256;
    int m0 = blockIdx.y * 64;
    int b  = blockIdx.z;
    const unsigned short* Ab = wpbf + (size_t)m0 * kC;
    const unsigned short* Bb = attnT + (size_t)b * kT * kC;

    int tid = threadIdx.x;
    int wave = tid >> 6, lane = tid & 63;
    int ln15 = lane & 15, quad = lane >> 4;
    int wm = wave >> 1, wt = wave & 1;

    f32x4 acc[2][8] = {};

    for (int k0 = 0; k0 < kC; k0 += 64) {
        __syncthreads();
        #pragma unroll
        for (int p = 0; p < 2; ++p) {
            int idx = tid + p * 256;
            int row = idx >> 3, seg = idx & 7;
            *(uint4*)&As[row * LDK + seg * 8] =
                *(const uint4*)&Ab[(size_t)row * kC + k0 + seg * 8];
        }
        #pragma unroll
        for (int p = 0; p < 8; ++p) {
            int idx = tid + p * 256;
            int row = idx >> 3, seg = idx & 7;
            *(uint4*)&Bs[row * LDK + seg * 8] =
                *(const uint4*)&Bb[(size_t)(t0 + row) * kC + k0 + seg * 8];
        }
        __syncthreads();
        #pragma unroll
        for (int ks = 0; ks < 2; ++ks) {
            bf16x8 af[2], bf[8];
            #pragma unroll
            for (int i = 0; i < 2; ++i)
                af[i] = *(bf16x8*)&As[(wm * 32 + i * 16 + ln15) * LDK + ks * 32 + quad * 8];
            #pragma unroll
            for (int j = 0; j < 8; ++j)
                bf[j] = *(bf16x8*)&Bs[(wt * 128 + j * 16 + ln15) * LDK + ks * 32 + quad * 8];
            #pragma unroll
            for (int i = 0; i < 2; ++i)
                #pragma unroll
                for (int j = 0; j < 8; ++j)
                    acc[i][j] = __builtin_amdgcn_mfma_f32_16x16x32_bf16(
                        af[i], bf[j], acc[i][j], 0, 0, 0);
        }
    }

    #pragma unroll
    for (int i = 0; i < 2; ++i) {
        float4 bv = *(const float4*)&proj_b[m0 + wm * 32 + i * 16 + quad * 4];
        const float* bp = (const float*)&bv;
        #pragma unroll
        for (int j = 0; j < 8; ++j) {
            int t = t0 + wt * 128 + j * 16 + ln15;
            int mbase = m0 + wm * 32 + i * 16 + quad * 4;
            #pragma unroll
            for (int r = 0; r < 4; ++r) {
                size_t off = ((size_t)b * kC + mbase + r) * kT + t;
                out[off] = acc[i][j][r] + bp[r] + x[off];
            }
        }
    }
}

// ---------------------------------------------------------------------------
extern "C" void kernel_launch(void* const* d_in, const int* in_sizes, int n_in,
                              void* d_out, int out_size, void* d_ws, size_t ws_size,
                              hipStream_t stream) {
    const float* x      = (const float*)d_in[0];
    const float* norm_w = (const float*)d_in[1];
    const float* norm_b = (const float*)d_in[2];
    const float* qkv_w  = (const float*)d_in[3];
    const float* qkv_b  = (const float*)d_in[4];
    const float* proj_w = (const float*)d_in[5];
    const float* proj_b = (const float*)d_in[6];
    float* out = (float*)d_out;

    // Workspace: stats fp32[512] (4 partials x 64 groups x {S,Q}) |
    // bf16: normT[4.19M] wbf[262144] qT kT vC attnT[4.19M each]
    float* stats = (float*)d_ws;
    unsigned short* wsbf  = (unsigned short*)((float*)d_ws + 512);
    unsigned short* normT = wsbf;
    unsigned short* wbf   = normT + (size_t)kB * kT * kC;
    unsigned short* qTp   = wbf + 262144;
    unsigned short* kTp   = qTp + (size_t)kB * kH * kT * kCh;
    unsigned short* vCp   = kTp + (size_t)kB * kH * kT * kCh;
    unsigned short* attnT = vCp + (size_t)kB * kH * kT * kCh;
    unsigned short* wpbf  = wbf + 196608;

    prep_kernel<<<384, 256, 0, stream>>>(x, stats, qkv_w, proj_w, wbf);
    gn_apply_t_kernel<<<dim3(kT / 64, kC / 64, kB), 256, 0, stream>>>(
        x, stats, norm_w, norm_b, normT);
    qkv_gemm_kernel<<<dim3(kT / 256, 12, kB), 256, 0, stream>>>(
        wbf, qkv_b, normT, qTp, kTp, vCp);
    attn_mfma_kernel<<<dim3(kT / 128, kB * kH), 256, 0, stream>>>(qTp, kTp, vCp, attnT);
    proj_gemm_kernel<<<dim3(kT / 256, kC / 64, kB), 256, 0, stream>>>(
        wpbf, proj_b, attnT, x, out);
}